// Round 8
// baseline (11676.221 us; speedup 1.0000x reference)
//
#include <hip/hip_runtime.h>
#include <hip/hip_bf16.h>
#include <math.h>

typedef __bf16 bf16x8 __attribute__((ext_vector_type(8)));
typedef float f32x4 __attribute__((ext_vector_type(4)));
typedef __hip_bfloat16 bf16s;

constexpr int kB = 16, kT = 24, kN = 2048, kD = 64;
constexpr size_t kBND = (size_t)kB * kN * kD;  // 2097152

// slot types: 0 = bf16 direct (global_load_lds), 1 = f32 (cvt), 2 = bf16+bf16 add
struct Slot { const void* p0; const void* p1; int astr0, trow0, astr1, trow1, type; };
struct Slots6 { Slot s[6]; };
struct DiffGrp { const bf16s* src; bf16s* oA; bf16s* oA2; };
struct DiffP { const bf16s* S0; const bf16s* S1; DiffGrp g[4]; int colsPerGrp; };

__device__ __forceinline__ void async_copy16(void* lds, const void* g) {
  __builtin_amdgcn_global_load_lds((const __attribute__((address_space(1))) void*)g,
                                   (__attribute__((address_space(3))) void*)lds,
                                   16, 0, 0);
}

// LDS tiles [rows][64] bf16 staged linearly; XOR swizzle on 16B chunks:
// source chunk (tid&7)^(row&7), read chunk g^(row&7). 0 conflicts (r3).
// r4: 256-thr/32KB/2+blocks-per-CU beats 512-thr/48KB operand sharing.
// r7: cg::grid.sync() costs ~80us; custom agent-scope barrier replaces it.

// ---------------- lean grid barrier (persistent kernel) ----------------
// release fence -> device-scope atomic arrive -> bounded spin -> acquire fence.
// Monotonic counter; every block calls it the same number of times.
__device__ __forceinline__ void grid_bar(unsigned* ctr, unsigned& gen, unsigned nb) {
  __syncthreads();
  if (threadIdx.x == 0) {
    __threadfence();                 // release: flush writes to shared L3
    atomicAdd(ctr, 1u);              // device-scope by default on CDNA
    gen += nb;
    const unsigned tgt = gen;
    int polls = 0;
    while (__hip_atomic_load(ctr, __ATOMIC_RELAXED, __HIP_MEMORY_SCOPE_AGENT) < tgt) {
      __builtin_amdgcn_s_sleep(8);
      if (++polls > 200000) break;   // fail-safe: never hang the queue
    }
    __threadfence();                 // acquire: invalidate local L1/L2
  }
  __syncthreads();
}

// ---------------- diffusion core ----------------
__device__ __forceinline__ void diff_core(
    const bf16s* __restrict__ S, const bf16s* __restrict__ Bsrc,
    int m0, int c0, bf16s* lA, bf16s* lB, f32x4 (&acc)[4][4])
{
  const int tid = threadIdx.x, lane = tid & 63, wave = tid >> 6;
  const int wm = (wave >> 1) * 64, wn = (wave & 1) * 64;
  const f32x4 zero = {0.f, 0.f, 0.f, 0.f};
#pragma unroll
  for (int i = 0; i < 4; ++i)
#pragma unroll
    for (int j = 0; j < 4; ++j) acc[i][j] = zero;

  const int ra = tid >> 3;
  const int cs = ((tid & 7) ^ (ra & 7)) * 8;
  const int rk0 = ((lane >> 4) ^ (lane & 7)) * 8;
  const int rk1 = ((4 + (lane >> 4)) ^ (lane & 7)) * 8;

  for (int k0 = 0; k0 < 2048; k0 += 64) {
#pragma unroll
    for (int i = 0; i < 4; ++i) {
      async_copy16(lA + (size_t)(i * 256 + tid) * 8,
                   S + (size_t)(m0 + i * 32 + ra) * 2048 + k0 + cs);
      async_copy16(lB + (size_t)(i * 256 + tid) * 8,
                   Bsrc + (size_t)(c0 + i * 32 + ra) * 2048 + k0 + cs);
    }
    __syncthreads();
#pragma unroll
    for (int ks = 0; ks < 2; ++ks) {
      const int rk = ks ? rk1 : rk0;
      bf16x8 av[4], bv[4];
#pragma unroll
      for (int f = 0; f < 4; ++f) {
        av[f] = *(const bf16x8*)(lA + (size_t)(wm + f * 16 + (lane & 15)) * 64 + rk);
        bv[f] = *(const bf16x8*)(lB + (size_t)(wn + f * 16 + (lane & 15)) * 64 + rk);
      }
#pragma unroll
      for (int i = 0; i < 4; ++i)
#pragma unroll
        for (int j = 0; j < 4; ++j)
          acc[i][j] = __builtin_amdgcn_mfma_f32_16x16x32_bf16(av[i], bv[j], acc[i][j], 0, 0, 0);
    }
    __syncthreads();
  }
}

__device__ __forceinline__ void diff_tile(
    const bf16s* __restrict__ S, const bf16s* __restrict__ src, bf16s* out,
    int m0, int c0, bf16s* lA, bf16s* lB)
{
  f32x4 acc[4][4];
  diff_core(S, src, m0, c0, lA, lB, acc);
  const int lane = threadIdx.x & 63, wave = threadIdx.x >> 6;
  const int wm = (wave >> 1) * 64, wn = (wave & 1) * 64;
  const int rq = (lane >> 4) * 4, cl = lane & 15;
#pragma unroll
  for (int fm = 0; fm < 4; ++fm)
#pragma unroll
    for (int fn = 0; fn < 4; ++fn)
#pragma unroll
      for (int q = 0; q < 4; ++q) {
        int gm = m0 + wm + fm * 16 + rq + q;
        int gc = c0 + wn + fn * 16 + cl;
        size_t off = ((size_t)(gc >> 6) * 2048 + gm) * 64 + (gc & 63);
        out[off] = __float2bfloat16(acc[fm][fn][q]);
      }
}

// ---------------- batched diffusion kernel (prologue) ----------------
__global__ __launch_bounds__(256) void k_diff(DiffP p)
{
  __shared__ bf16s lA[128 * 64];
  __shared__ bf16s lB[128 * 64];
  const int mi = blockIdx.x;
  const bf16s* S = (mi >> 4) ? p.S1 : p.S0;
  const int m0 = (mi & 15) * 128;
  const int ybpg = p.colsPerGrp >> 7;
  const int grp = blockIdx.y / ybpg;
  const int c0 = (blockIdx.y - grp * ybpg) * 128;
  const DiffGrp G = p.g[grp];
  bf16s* out = (mi >> 4) ? G.oA2 : G.oA;
  diff_tile(S, G.src, out, m0, c0, lA, lB);
}

// ---------------- setup: A2 = 2*A@A - I ----------------
__global__ __launch_bounds__(256) void k_a2(
    const bf16s* __restrict__ A, const bf16s* __restrict__ AT, bf16s* A2)
{
  __shared__ bf16s lA[128 * 64];
  __shared__ bf16s lB[128 * 64];
  const int m0 = blockIdx.x * 128, n0 = blockIdx.y * 128;
  f32x4 acc[4][4];
  diff_core(A, AT, m0, n0, lA, lB, acc);
  const int lane = threadIdx.x & 63, wave = threadIdx.x >> 6;
  const int wm = (wave >> 1) * 64, wn = (wave & 1) * 64;
  const int rq = (lane >> 4) * 4, cl = lane & 15;
#pragma unroll
  for (int fm = 0; fm < 4; ++fm)
#pragma unroll
    for (int fn = 0; fn < 4; ++fn)
#pragma unroll
      for (int q = 0; q < 4; ++q) {
        int gm = m0 + wm + fm * 16 + rq + q;
        int gc = n0 + wn + fn * 16 + cl;
        A2[(size_t)gm * 2048 + gc] = __float2bfloat16(2.f * acc[fm][fn][q] - (gm == gc ? 1.f : 0.f));
      }
}

// =============== small GEMM core (gate/cand): K = 6 slots of 64 ===============
template<int BN>
__device__ __forceinline__ void small_core(
    const Slots6& sl, int m0, const bf16s* __restrict__ W,
    bf16s* lA, bf16s* lB, f32x4 (&acc)[4][BN / 32])
{
  const int tid = threadIdx.x, lane = tid & 63, wave = tid >> 6;
  const int wm = (wave >> 1) * 64, wn = (wave & 1) * (BN / 2);
  const f32x4 zero = {0.f, 0.f, 0.f, 0.f};
#pragma unroll
  for (int i = 0; i < 4; ++i)
#pragma unroll
    for (int j = 0; j < BN / 32; ++j) acc[i][j] = zero;

  const int ra = tid >> 3;
  const int cs = ((tid & 7) ^ (ra & 7)) * 8;
  const int rk0 = ((lane >> 4) ^ (lane & 7)) * 8;
  const int rk1 = ((4 + (lane >> 4)) ^ (lane & 7)) * 8;

#pragma unroll
  for (int ks = 0; ks < 6; ++ks) {
    const Slot sd = sl.s[ks];
    if (sd.type == 0) {
      const bf16s* base = (const bf16s*)sd.p0;
#pragma unroll
      for (int i = 0; i < 4; ++i) {
        int row = m0 + i * 32 + ra;
        size_t roff = ((size_t)(row >> 11) * sd.astr0 + sd.trow0 + (row & 2047)) * 64 + cs;
        async_copy16(lA + (size_t)(i * 256 + tid) * 8, base + roff);
      }
    } else if (sd.type == 1) {
#pragma unroll
      for (int i = 0; i < 4; ++i) {
        int row = m0 + i * 32 + ra;
        size_t roff = ((size_t)(row >> 11) * sd.astr0 + sd.trow0 + (row & 2047)) * 64 + cs;
        const float4* q0 = (const float4*)((const float*)sd.p0 + roff);
        float4 a = q0[0], b = q0[1];
        union { bf16x8 v; bf16s h[8]; } u;
        u.h[0] = __float2bfloat16(a.x); u.h[1] = __float2bfloat16(a.y);
        u.h[2] = __float2bfloat16(a.z); u.h[3] = __float2bfloat16(a.w);
        u.h[4] = __float2bfloat16(b.x); u.h[5] = __float2bfloat16(b.y);
        u.h[6] = __float2bfloat16(b.z); u.h[7] = __float2bfloat16(b.w);
        *(bf16x8*)(lA + (size_t)(i * 256 + tid) * 8) = u.v;
      }
    } else {
#pragma unroll
      for (int i = 0; i < 4; ++i) {
        int row = m0 + i * 32 + ra;
        size_t r0o = ((size_t)(row >> 11) * sd.astr0 + sd.trow0 + (row & 2047)) * 64 + cs;
        size_t r1o = ((size_t)(row >> 11) * sd.astr1 + sd.trow1 + (row & 2047)) * 64 + cs;
        union { bf16x8 v; bf16s h[8]; } a, b, o;
        a.v = *(const bf16x8*)((const bf16s*)sd.p0 + r0o);
        b.v = *(const bf16x8*)((const bf16s*)sd.p1 + r1o);
#pragma unroll
        for (int j = 0; j < 8; ++j)
          o.h[j] = __float2bfloat16(__bfloat162float(a.h[j]) + __bfloat162float(b.h[j]));
        *(bf16x8*)(lA + (size_t)(i * 256 + tid) * 8) = o.v;
      }
    }
#pragma unroll
    for (int i = 0; i < BN / 32; ++i)
      async_copy16(lB + (size_t)(i * 256 + tid) * 8,
                   W + (size_t)(i * 32 + ra) * 384 + ks * 64 + cs);
    __syncthreads();
#pragma unroll
    for (int kss = 0; kss < 2; ++kss) {
      const int rk = kss ? rk1 : rk0;
      bf16x8 av[4], bv[BN / 32];
#pragma unroll
      for (int f = 0; f < 4; ++f)
        av[f] = *(const bf16x8*)(lA + (size_t)(wm + f * 16 + (lane & 15)) * 64 + rk);
#pragma unroll
      for (int f = 0; f < BN / 32; ++f)
        bv[f] = *(const bf16x8*)(lB + (size_t)(wn + f * 16 + (lane & 15)) * 64 + rk);
#pragma unroll
      for (int i = 0; i < 4; ++i)
#pragma unroll
        for (int j = 0; j < BN / 32; ++j)
          acc[i][j] = __builtin_amdgcn_mfma_f32_16x16x32_bf16(av[i], bv[j], acc[i][j], 0, 0, 0);
    }
    __syncthreads();
  }
}

// ---------------- gate / cand tiles ----------------
struct LayerG {
  Slots6 sl; const bf16s* W; const float* bias;
  const float* h; bf16s* zh; bf16s* zhT; float* r;
};
__device__ __forceinline__ void gate_tile(const LayerG& L, int m0, bf16s* lA, bf16s* lB)
{
  f32x4 acc[4][4];
  small_core<128>(L.sl, m0, L.W, lA, lB, acc);
  const int lane = threadIdx.x & 63, wave = threadIdx.x >> 6;
  const int wm = (wave >> 1) * 64, wn = (wave & 1) * 64;
  const int rq = (lane >> 4) * 4, cl = lane & 15;
#pragma unroll
  for (int fm = 0; fm < 4; ++fm)
#pragma unroll
    for (int fn = 0; fn < 4; ++fn) {
      const int o = wn + fn * 16 + cl;
      const float bias = L.bias[o];
#pragma unroll
      for (int q = 0; q < 4; ++q) {
        size_t gm = (size_t)m0 + wm + fm * 16 + rq + q;
        float s = 1.f / (1.f + expf(-(acc[fm][fn][q] + bias)));
        if (o < 64) {
          float zh = s * L.h[gm * 64 + o];
          L.zh[gm * 64 + o] = __float2bfloat16(zh);
          L.zhT[((size_t)((gm >> 11) * 64 + o)) * 2048 + (gm & 2047)] = __float2bfloat16(zh);
        } else {
          L.r[gm * 64 + (o - 64)] = s;
        }
      }
    }
}

struct LayerC {
  Slots6 sl; const bf16s* W; const float* bias;
  const float* r; float* h32; bf16s* hT; bf16s* h_bf; float* hid;
  bf16s* x1; float* outC; const float* x0; int t;
};
__device__ __forceinline__ void cand_tile(const LayerC& L, int m0, bf16s* lA, bf16s* lB)
{
  f32x4 acc[4][2];
  small_core<64>(L.sl, m0, L.W, lA, lB, acc);
  const int lane = threadIdx.x & 63, wave = threadIdx.x >> 6;
  const int wm = (wave >> 1) * 64, wn = (wave & 1) * 32;
  const int rq = (lane >> 4) * 4, cl = lane & 15;
#pragma unroll
  for (int fm = 0; fm < 4; ++fm)
#pragma unroll
    for (int fn = 0; fn < 2; ++fn) {
      const int d = wn + fn * 16 + cl;
      const float bias = L.bias[d];
#pragma unroll
      for (int q = 0; q < 4; ++q) {
        size_t gm = (size_t)m0 + wm + fm * 16 + rq + q;
        float hc = tanhf(acc[fm][fn][q] + bias);
        float r = L.r[gm * 64 + d];
        float h = L.h32[gm * 64 + d];
        float hn = r * h + (1.f - r) * hc;
        L.h32[gm * 64 + d] = hn;
        int b = (int)(gm >> 11), n = (int)(gm & 2047);
        L.hT[((size_t)(b * 64 + d)) * 2048 + n] = __float2bfloat16(hn);
        L.h_bf[gm * 64 + d] = __float2bfloat16(hn);
        size_t xi = (((size_t)b * kT + L.t) * 2048 + n) * 64 + d;
        if (L.x1) L.x1[gm * 64 + d] = __float2bfloat16(L.x0[xi] + hn);
        if (L.outC) L.outC[xi] = L.x0[xi] + hn;
        if (L.hid) L.hid[gm * 64 + d] = hn;
      }
    }
}

__device__ __forceinline__ Slot Sb_d(const void* p0, int astr, int trow) {
  return Slot{p0, nullptr, astr, trow, 0, 0, 0};
}
__device__ __forceinline__ Slot Sf_d(const void* p0, int astr, int trow) {
  return Slot{p0, nullptr, astr, trow, 0, 0, 1};
}
__device__ __forceinline__ Slot S2_d(const void* p0, const void* p1, int astr1, int trow1) {
  return Slot{p0, p1, 2048, 0, astr1, trow1, 2};
}

// =============== persistent superstep kernel: 512 blocks x 256 thr ===============
struct SuperP {
  const bf16s *A, *A2, *AxF, *A2xF;
  const float *x;
  const bf16s *WgT, *WuT; const float *bg, *bu;
  float *h32_0, *h32_1, *r32_0, *r32_1;
  bf16s *hT0, *hT1, *hbf0, *hbf1;
  bf16s *zhT0, *zhT1, *zhbf0, *zhbf1;
  bf16s *x1b;
  bf16s *sAh0, *sA2h0, *sAh1, *sA2h1, *sZ0, *sA2Z0, *sZ1, *sA2Z1;
  float *outCur, *outHid;
  unsigned *bar;
};

__device__ __forceinline__ int swz_tile512(int b) {
  // XCD-chunked bijection on [0,512): XCD (b&7) gets 64 contiguous tiles
  return ((b & 7) << 6) | (b >> 3);
}

__global__ __launch_bounds__(256, 2) void k_super(SuperP P)
{
  __shared__ bf16s lA[128 * 64];
  __shared__ bf16s lB[128 * 64];
  const int bid = blockIdx.x;
  const unsigned nb = gridDim.x;
  unsigned gen = 0;

  // diffusion tile decode (fixed per block)
  const int v = swz_tile512(bid);
  const int dg = v >> 8;                 // group 0/1 (layer)
  const int dt = v & 255;
  const int dsp = dt >> 7;               // support select (A / A2)
  const int dm0 = ((dt >> 3) & 15) * 128;
  const int dc0 = (dt & 7) * 128;
  const bool isA = bid < 256;            // gate/cand layer select
  const int gm0 = (bid & 255) * 128;

  for (int s = 0; s <= kT; ++s) {
    const bool aA = (s < kT), aB = (s >= 1);
    const int tA = s, tB = s - 1;
    bf16s* x1cur  = P.x1b + (size_t)(s & 1) * kBND;
    bf16s* x1prev = P.x1b + (size_t)((s - 1) & 1) * kBND;

    // ---- phase 0: diffuse h0 (always) and h1 (if aB) ----
    if (dg == 0 || aB) {
      const bf16s* S = dsp ? P.A2 : P.A;
      const bf16s* src = dg ? P.hT1 : P.hT0;
      bf16s* out = dg ? (dsp ? P.sA2h1 : P.sAh1) : (dsp ? P.sA2h0 : P.sAh0);
      diff_tile(S, src, out, dm0, dc0, lA, lB);
    }
    grid_bar(P.bar, gen, nb);

    // ---- gate ----
    if (isA ? aA : aB) {
      LayerG L;
      if (isA) {
        L.sl.s[0] = Sf_d(P.x, kT * 2048, tA * 2048);
        L.sl.s[1] = Sb_d(P.hbf0, 2048, 0);
        L.sl.s[2] = Sb_d(P.AxF, kT * 2048, tA * 2048);
        L.sl.s[3] = Sb_d(P.sAh0, 2048, 0);
        L.sl.s[4] = Sb_d(P.A2xF, kT * 2048, tA * 2048);
        L.sl.s[5] = Sb_d(P.sA2h0, 2048, 0);
        L.W = P.WgT; L.bias = P.bg; L.h = P.h32_0;
        L.zh = P.zhbf0; L.zhT = P.zhT0; L.r = P.r32_0;
      } else {
        L.sl.s[0] = Sb_d(x1prev, 2048, 0);
        L.sl.s[1] = Sb_d(P.hbf1, 2048, 0);
        L.sl.s[2] = S2_d(P.sAh0, P.AxF, kT * 2048, tB * 2048);   // A@x1 = A@h0 + A@x
        L.sl.s[3] = Sb_d(P.sAh1, 2048, 0);
        L.sl.s[4] = S2_d(P.sA2h0, P.A2xF, kT * 2048, tB * 2048);
        L.sl.s[5] = Sb_d(P.sA2h1, 2048, 0);
        L.W = P.WgT + (size_t)128 * 384; L.bias = P.bg + 128; L.h = P.h32_1;
        L.zh = P.zhbf1; L.zhT = P.zhT1; L.r = P.r32_1;
      }
      gate_tile(L, gm0, lA, lB);
    }
    grid_bar(P.bar, gen, nb);

    // ---- phase 1: diffuse zh0 (aA) / zh1 (aB) ----
    if (dg ? aB : aA) {
      const bf16s* S = dsp ? P.A2 : P.A;
      const bf16s* src = dg ? P.zhT1 : P.zhT0;
      bf16s* out = dg ? (dsp ? P.sA2Z1 : P.sZ1) : (dsp ? P.sA2Z0 : P.sZ0);
      diff_tile(S, src, out, dm0, dc0, lA, lB);
    }
    grid_bar(P.bar, gen, nb);

    // ---- candidate + GRU update ----
    if (isA ? aA : aB) {
      LayerC L;
      if (isA) {
        L.sl.s[0] = Sf_d(P.x, kT * 2048, tA * 2048);
        L.sl.s[1] = Sb_d(P.zhbf0, 2048, 0);
        L.sl.s[2] = Sb_d(P.AxF, kT * 2048, tA * 2048);
        L.sl.s[3] = Sb_d(P.sZ0, 2048, 0);
        L.sl.s[4] = Sb_d(P.A2xF, kT * 2048, tA * 2048);
        L.sl.s[5] = Sb_d(P.sA2Z0, 2048, 0);
        L.W = P.WuT; L.bias = P.bu; L.r = P.r32_0; L.h32 = P.h32_0;
        L.hT = P.hT0; L.h_bf = P.hbf0;
        L.hid = (tA == kT - 1) ? P.outHid : nullptr;
        L.x1 = x1cur; L.outC = nullptr; L.x0 = P.x; L.t = tA;
      } else {
        L.sl.s[0] = Sb_d(x1prev, 2048, 0);
        L.sl.s[1] = Sb_d(P.zhbf1, 2048, 0);
        L.sl.s[2] = S2_d(P.sAh0, P.AxF, kT * 2048, tB * 2048);
        L.sl.s[3] = Sb_d(P.sZ1, 2048, 0);
        L.sl.s[4] = S2_d(P.sA2h0, P.A2xF, kT * 2048, tB * 2048);
        L.sl.s[5] = Sb_d(P.sA2Z1, 2048, 0);
        L.W = P.WuT + (size_t)64 * 384; L.bias = P.bu + 64; L.r = P.r32_1; L.h32 = P.h32_1;
        L.hT = P.hT1; L.h_bf = P.hbf1;
        L.hid = (tB == kT - 1) ? P.outHid + kBND : nullptr;
        L.x1 = nullptr; L.outC = P.outCur; L.x0 = P.x; L.t = tB;
      }
      cand_tile(L, gm0, lA, lB);
    }
    grid_bar(P.bar, gen, nb);
  }
}

// ---------------- utility kernels ----------------
__global__ __launch_bounds__(256) void transpose_cvt(
    const float* in, bf16s* out, int nrows, int ncols,
    size_t in_ostride, size_t out_ostride)
{
  __shared__ float tile[64][65];
  const int r0 = blockIdx.x * 64, c0 = blockIdx.y * 64;
  in  += (size_t)blockIdx.z * in_ostride;
  out += (size_t)blockIdx.z * out_ostride;
  const int tx = threadIdx.x & 63, ty = threadIdx.x >> 6;
#pragma unroll
  for (int i = 0; i < 64; i += 4)
    tile[ty + i][tx] = in[(size_t)(r0 + ty + i) * ncols + c0 + tx];
  __syncthreads();
#pragma unroll
  for (int i = 0; i < 64; i += 4)
    out[(size_t)(c0 + ty + i) * nrows + r0 + tx] = __float2bfloat16(tile[tx][ty + i]);
}

__global__ __launch_bounds__(256) void k_cvt(const float* in, bf16s* out, int n)
{
  int i = blockIdx.x * 256 + threadIdx.x;
  if (i < n) out[i] = __float2bfloat16(in[i]);
}

__global__ __launch_bounds__(256) void k_repack(
    const float* Wg, const float* Wu, bf16s* WgT, bf16s* WuT)
{
  int idx = blockIdx.x * 256 + threadIdx.x;
  if (idx < 2 * 3 * 128 * 128) {
    int o = idx & 127, cin = (idx >> 7) & 127, k = (idx >> 14) % 3, l = idx / 49152;
    WgT[((size_t)(l * 128 + o)) * 384 + (2 * k + (cin >> 6)) * 64 + (cin & 63)] =
        __float2bfloat16(Wg[idx]);
  }
  if (idx < 2 * 3 * 128 * 64) {
    int o = idx & 63, cin = (idx >> 6) & 127, k = (idx >> 13) % 3, l = idx / 24576;
    WuT[((size_t)(l * 64 + o)) * 384 + (2 * k + (cin >> 6)) * 64 + (cin & 63)] =
        __float2bfloat16(Wu[idx]);
  }
}

__global__ __launch_bounds__(256) void init_layer(
    const float* ist_l, float* h32, bf16s* hT, bf16s* h_bf)
{
  size_t idx = (size_t)blockIdx.x * 256 + threadIdx.x;
  if (idx >= kBND) return;
  int d = (int)(idx & 63);
  size_t row = idx >> 6;
  int n = (int)(row & 2047), b = (int)(row >> 11);
  float h = ist_l[idx];
  h32[idx] = h;
  hT[((size_t)(b * 64 + d)) * 2048 + n] = __float2bfloat16(h);
  h_bf[idx] = __float2bfloat16(h);
}

// ---------------- host orchestration ----------------
extern "C" void kernel_launch(void* const* d_in, const int* in_sizes, int n_in,
                              void* d_out, int out_size, void* d_ws, size_t ws_size,
                              hipStream_t stream)
{
  (void)in_sizes; (void)n_in; (void)out_size; (void)ws_size;
  const float* x   = (const float*)d_in[0];
  const float* ist = (const float*)d_in[1];
  const float* adj = (const float*)d_in[2];
  const float* Wg  = (const float*)d_in[3];
  const float* bg  = (const float*)d_in[4];
  const float* Wu  = (const float*)d_in[5];
  const float* bu  = (const float*)d_in[6];
  float* outCur = (float*)d_out;
  float* outHid = outCur + (size_t)kB * kT * kN * kD;

  char* p = (char*)d_ws;
  auto carve = [&](size_t bytes) { char* q = p; p += (bytes + 255) & ~(size_t)255; return q; };
  unsigned* bctr = (unsigned*)carve(256);
  bf16s* A_bf  = (bf16s*)carve((size_t)2048 * 2048 * 2);
  bf16s* A2_bf = (bf16s*)carve((size_t)2048 * 2048 * 2);
  bf16s* WgT   = (bf16s*)carve((size_t)2 * 128 * 384 * 2);
  bf16s* WuT   = (bf16s*)carve((size_t)2 * 64 * 384 * 2);
  float* h32b  = (float*)carve(2 * kBND * 4);
  float* r32b  = (float*)carve(2 * kBND * 4);
  bf16s* hTb   = (bf16s*)carve(2 * kBND * 2);
  bf16s* hbfb  = (bf16s*)carve(2 * kBND * 2);
  bf16s* zhTb  = (bf16s*)carve(2 * kBND * 2);
  bf16s* zhbfb = (bf16s*)carve(2 * kBND * 2);
  bf16s* x1b   = (bf16s*)carve(2 * kBND * 2);
  bf16s* sAh0  = (bf16s*)carve(kBND * 2);
  bf16s* sA2h0 = (bf16s*)carve(kBND * 2);
  bf16s* sAh1  = (bf16s*)carve(kBND * 2);
  bf16s* sA2h1 = (bf16s*)carve(kBND * 2);
  bf16s* sZ0   = (bf16s*)carve(kBND * 2);
  bf16s* sA2Z0 = (bf16s*)carve(kBND * 2);
  bf16s* sZ1   = (bf16s*)carve(kBND * 2);
  bf16s* sA2Z1 = (bf16s*)carve(kBND * 2);
  const size_t xTfull = (size_t)kB * kT * kD * kN * 2;   // 96 MiB
  bf16s* AxF  = (bf16s*)carve(xTfull);
  bf16s* A2xF = (bf16s*)carve(xTfull);
  bf16s* xTh  = (bf16s*)carve(xTfull / 2);
  bf16s* AT_bf = AxF;   // alias: AT dead (after k_a2) before AxF is written

  // ---- setup ----
  hipMemsetAsync(bctr, 0, 256, stream);
  k_cvt<<<dim3((2048 * 2048 + 255) / 256), 256, 0, stream>>>(adj, A_bf, 2048 * 2048);
  transpose_cvt<<<dim3(32, 32, 1), 256, 0, stream>>>(adj, AT_bf, 2048, 2048, 0, 0);
  k_a2<<<dim3(16, 16, 1), 256, 0, stream>>>(A_bf, AT_bf, A2_bf);
  k_repack<<<dim3(384), 256, 0, stream>>>(Wg, Wu, WgT, WuT);
  init_layer<<<dim3((int)(kBND / 256)), 256, 0, stream>>>(ist, h32b, hTb, hbfb);
  init_layer<<<dim3((int)(kBND / 256)), 256, 0, stream>>>(ist + kBND, h32b + kBND, hTb + kBND, hbfb + kBND);

  // ---- batched layer-0 x-diffusion (two b-halves) ----
  for (int h = 0; h < 2; ++h) {
    size_t off = (size_t)h * 8 * kT * 131072;
    transpose_cvt<<<dim3(32, 1, 8 * kT), 256, 0, stream>>>(x + off, xTh, 2048, 64, 131072, 131072);
    DiffP dp; dp.S0 = A_bf; dp.S1 = A2_bf; dp.colsPerGrp = 12288;
    dp.g[0] = DiffGrp{xTh, AxF + off, A2xF + off};
    dp.g[1] = dp.g[2] = dp.g[3] = DiffGrp{nullptr, nullptr, nullptr};
    k_diff<<<dim3(32, 96), 256, 0, stream>>>(dp);
  }

  // ---- persistent superstep loop (plain launch, custom barrier) ----
  SuperP P;
  P.A = A_bf; P.A2 = A2_bf; P.AxF = AxF; P.A2xF = A2xF;
  P.x = x; P.WgT = WgT; P.WuT = WuT; P.bg = bg; P.bu = bu;
  P.h32_0 = h32b; P.h32_1 = h32b + kBND;
  P.r32_0 = r32b; P.r32_1 = r32b + kBND;
  P.hT0 = hTb; P.hT1 = hTb + kBND;
  P.hbf0 = hbfb; P.hbf1 = hbfb + kBND;
  P.zhT0 = zhTb; P.zhT1 = zhTb + kBND;
  P.zhbf0 = zhbfb; P.zhbf1 = zhbfb + kBND;
  P.x1b = x1b;
  P.sAh0 = sAh0; P.sA2h0 = sA2h0; P.sAh1 = sAh1; P.sA2h1 = sA2h1;
  P.sZ0 = sZ0; P.sA2Z0 = sA2Z0; P.sZ1 = sZ1; P.sA2Z1 = sA2Z1;
  P.outCur = outCur; P.outHid = outHid;
  P.bar = bctr;
  k_super<<<dim3(512), dim3(256), 0, stream>>>(P);
}

// Round 9
// 8750.037 us; speedup vs baseline: 1.3344x; 1.3344x over previous
//
#include <hip/hip_runtime.h>
#include <hip/hip_bf16.h>
#include <math.h>

typedef __bf16 bf16x8 __attribute__((ext_vector_type(8)));
typedef float f32x4 __attribute__((ext_vector_type(4)));
typedef __hip_bfloat16 bf16s;

constexpr int kB = 16, kT = 24, kN = 2048, kD = 64;
constexpr size_t kBND = (size_t)kB * kN * kD;  // 2097152
constexpr int kNSTG = (kT + 1) * 4;            // 100 barrier stages

// slot types: 0 = bf16 direct (global_load_lds), 1 = f32 (cvt), 2 = bf16+bf16 add
struct Slot { const void* p0; const void* p1; int astr0, trow0, astr1, trow1, type; };
struct Slots6 { Slot s[6]; };
struct DiffGrp { const bf16s* src; bf16s* oA; bf16s* oA2; };
struct DiffP { const bf16s* S0; const bf16s* S1; DiffGrp g[4]; int colsPerGrp; };

__device__ __forceinline__ void async_copy16(void* lds, const void* g) {
  __builtin_amdgcn_global_load_lds((const __attribute__((address_space(1))) void*)g,
                                   (__attribute__((address_space(3))) void*)lds,
                                   16, 0, 0);
}

// LDS tiles [rows][64] bf16 staged linearly; XOR swizzle on 16B chunks:
// source chunk (tid&7)^(row&7), read chunk g^(row&7). 0 conflicts (r3).
// r4: 256-thr/32KB/2 blocks-per-CU beats 512-thr/48KB operand sharing.
// r7/r8: single-counter grid barriers cost ~85us (512 serialized RMWs on one
// line). r9: 8-way split arrival counters + leader-published release flag.

// ---------------- split-counter grid barrier ----------------
// bar layout: stage g arrival slots = bar + (g*8+slot)*32 ; release flag =
// bar + (800+g)*32. All 128B-padded. Every block arrives at every stage.
__device__ __forceinline__ void grid_bar(unsigned* bar, int g, unsigned nb) {
  __syncthreads();
  if (threadIdx.x == 0) {
    __threadfence();                                   // release (agent scope)
    atomicAdd(bar + ((unsigned)g * 8u + (blockIdx.x & 7u)) * 32u, 1u);
    unsigned* rel = bar + (800u + (unsigned)g) * 32u;
    if (blockIdx.x == 0) {
      int polls = 0;
      for (;;) {
        unsigned sum = 0;
#pragma unroll
        for (int i = 0; i < 8; ++i)
          sum += __hip_atomic_load(bar + ((unsigned)g * 8u + i) * 32u,
                                   __ATOMIC_RELAXED, __HIP_MEMORY_SCOPE_AGENT);
        if (sum >= nb) break;
        __builtin_amdgcn_s_sleep(2);
        if (++polls > 4000000) break;                  // fail-safe
      }
      __hip_atomic_store(rel, 1u, __ATOMIC_RELAXED, __HIP_MEMORY_SCOPE_AGENT);
    } else {
      int polls = 0;
      while (__hip_atomic_load(rel, __ATOMIC_RELAXED, __HIP_MEMORY_SCOPE_AGENT) == 0u) {
        __builtin_amdgcn_s_sleep(8);
        if (++polls > 1000000) break;                  // fail-safe
      }
    }
    __threadfence();                                   // acquire
  }
  __syncthreads();
}

// ---------------- diffusion core ----------------
__device__ __forceinline__ void diff_core(
    const bf16s* __restrict__ S, const bf16s* __restrict__ Bsrc,
    int m0, int c0, bf16s* lA, bf16s* lB, f32x4 (&acc)[4][4])
{
  const int tid = threadIdx.x, lane = tid & 63, wave = tid >> 6;
  const int wm = (wave >> 1) * 64, wn = (wave & 1) * 64;
  const f32x4 zero = {0.f, 0.f, 0.f, 0.f};
#pragma unroll
  for (int i = 0; i < 4; ++i)
#pragma unroll
    for (int j = 0; j < 4; ++j) acc[i][j] = zero;

  const int ra = tid >> 3;
  const int cs = ((tid & 7) ^ (ra & 7)) * 8;
  const int rk0 = ((lane >> 4) ^ (lane & 7)) * 8;
  const int rk1 = ((4 + (lane >> 4)) ^ (lane & 7)) * 8;

  for (int k0 = 0; k0 < 2048; k0 += 64) {
#pragma unroll
    for (int i = 0; i < 4; ++i) {
      async_copy16(lA + (size_t)(i * 256 + tid) * 8,
                   S + (size_t)(m0 + i * 32 + ra) * 2048 + k0 + cs);
      async_copy16(lB + (size_t)(i * 256 + tid) * 8,
                   Bsrc + (size_t)(c0 + i * 32 + ra) * 2048 + k0 + cs);
    }
    __syncthreads();
#pragma unroll
    for (int ks = 0; ks < 2; ++ks) {
      const int rk = ks ? rk1 : rk0;
      bf16x8 av[4], bv[4];
#pragma unroll
      for (int f = 0; f < 4; ++f) {
        av[f] = *(const bf16x8*)(lA + (size_t)(wm + f * 16 + (lane & 15)) * 64 + rk);
        bv[f] = *(const bf16x8*)(lB + (size_t)(wn + f * 16 + (lane & 15)) * 64 + rk);
      }
#pragma unroll
      for (int i = 0; i < 4; ++i)
#pragma unroll
        for (int j = 0; j < 4; ++j)
          acc[i][j] = __builtin_amdgcn_mfma_f32_16x16x32_bf16(av[i], bv[j], acc[i][j], 0, 0, 0);
    }
    __syncthreads();
  }
}

__device__ __forceinline__ void diff_tile(
    const bf16s* __restrict__ S, const bf16s* __restrict__ src, bf16s* out,
    int m0, int c0, bf16s* lA, bf16s* lB)
{
  f32x4 acc[4][4];
  diff_core(S, src, m0, c0, lA, lB, acc);
  const int lane = threadIdx.x & 63, wave = threadIdx.x >> 6;
  const int wm = (wave >> 1) * 64, wn = (wave & 1) * 64;
  const int rq = (lane >> 4) * 4, cl = lane & 15;
#pragma unroll
  for (int fm = 0; fm < 4; ++fm)
#pragma unroll
    for (int fn = 0; fn < 4; ++fn)
#pragma unroll
      for (int q = 0; q < 4; ++q) {
        int gm = m0 + wm + fm * 16 + rq + q;
        int gc = c0 + wn + fn * 16 + cl;
        size_t off = ((size_t)(gc >> 6) * 2048 + gm) * 64 + (gc & 63);
        out[off] = __float2bfloat16(acc[fm][fn][q]);
      }
}

// ---------------- batched diffusion kernel (prologue) ----------------
__global__ __launch_bounds__(256) void k_diff(DiffP p)
{
  __shared__ bf16s lA[128 * 64];
  __shared__ bf16s lB[128 * 64];
  const int mi = blockIdx.x;
  const bf16s* S = (mi >> 4) ? p.S1 : p.S0;
  const int m0 = (mi & 15) * 128;
  const int ybpg = p.colsPerGrp >> 7;
  const int grp = blockIdx.y / ybpg;
  const int c0 = (blockIdx.y - grp * ybpg) * 128;
  const DiffGrp G = p.g[grp];
  bf16s* out = (mi >> 4) ? G.oA2 : G.oA;
  diff_tile(S, G.src, out, m0, c0, lA, lB);
}

// ---------------- setup: A2 = 2*A@A - I ----------------
__global__ __launch_bounds__(256) void k_a2(
    const bf16s* __restrict__ A, const bf16s* __restrict__ AT, bf16s* A2)
{
  __shared__ bf16s lA[128 * 64];
  __shared__ bf16s lB[128 * 64];
  const int m0 = blockIdx.x * 128, n0 = blockIdx.y * 128;
  f32x4 acc[4][4];
  diff_core(A, AT, m0, n0, lA, lB, acc);
  const int lane = threadIdx.x & 63, wave = threadIdx.x >> 6;
  const int wm = (wave >> 1) * 64, wn = (wave & 1) * 64;
  const int rq = (lane >> 4) * 4, cl = lane & 15;
#pragma unroll
  for (int fm = 0; fm < 4; ++fm)
#pragma unroll
    for (int fn = 0; fn < 4; ++fn)
#pragma unroll
      for (int q = 0; q < 4; ++q) {
        int gm = m0 + wm + fm * 16 + rq + q;
        int gc = n0 + wn + fn * 16 + cl;
        A2[(size_t)gm * 2048 + gc] = __float2bfloat16(2.f * acc[fm][fn][q] - (gm == gc ? 1.f : 0.f));
      }
}

// =============== small GEMM core (gate/cand): K = 6 slots of 64 ===============
template<int BN>
__device__ __forceinline__ void small_core(
    const Slots6& sl, int m0, const bf16s* __restrict__ W,
    bf16s* lA, bf16s* lB, f32x4 (&acc)[4][BN / 32])
{
  const int tid = threadIdx.x, lane = tid & 63, wave = tid >> 6;
  const int wm = (wave >> 1) * 64, wn = (wave & 1) * (BN / 2);
  const f32x4 zero = {0.f, 0.f, 0.f, 0.f};
#pragma unroll
  for (int i = 0; i < 4; ++i)
#pragma unroll
    for (int j = 0; j < BN / 32; ++j) acc[i][j] = zero;

  const int ra = tid >> 3;
  const int cs = ((tid & 7) ^ (ra & 7)) * 8;
  const int rk0 = ((lane >> 4) ^ (lane & 7)) * 8;
  const int rk1 = ((4 + (lane >> 4)) ^ (lane & 7)) * 8;

#pragma unroll
  for (int ks = 0; ks < 6; ++ks) {
    const Slot sd = sl.s[ks];
    if (sd.type == 0) {
      const bf16s* base = (const bf16s*)sd.p0;
#pragma unroll
      for (int i = 0; i < 4; ++i) {
        int row = m0 + i * 32 + ra;
        size_t roff = ((size_t)(row >> 11) * sd.astr0 + sd.trow0 + (row & 2047)) * 64 + cs;
        async_copy16(lA + (size_t)(i * 256 + tid) * 8, base + roff);
      }
    } else if (sd.type == 1) {
#pragma unroll
      for (int i = 0; i < 4; ++i) {
        int row = m0 + i * 32 + ra;
        size_t roff = ((size_t)(row >> 11) * sd.astr0 + sd.trow0 + (row & 2047)) * 64 + cs;
        const float4* q0 = (const float4*)((const float*)sd.p0 + roff);
        float4 a = q0[0], b = q0[1];
        union { bf16x8 v; bf16s h[8]; } u;
        u.h[0] = __float2bfloat16(a.x); u.h[1] = __float2bfloat16(a.y);
        u.h[2] = __float2bfloat16(a.z); u.h[3] = __float2bfloat16(a.w);
        u.h[4] = __float2bfloat16(b.x); u.h[5] = __float2bfloat16(b.y);
        u.h[6] = __float2bfloat16(b.z); u.h[7] = __float2bfloat16(b.w);
        *(bf16x8*)(lA + (size_t)(i * 256 + tid) * 8) = u.v;
      }
    } else {
#pragma unroll
      for (int i = 0; i < 4; ++i) {
        int row = m0 + i * 32 + ra;
        size_t r0o = ((size_t)(row >> 11) * sd.astr0 + sd.trow0 + (row & 2047)) * 64 + cs;
        size_t r1o = ((size_t)(row >> 11) * sd.astr1 + sd.trow1 + (row & 2047)) * 64 + cs;
        union { bf16x8 v; bf16s h[8]; } a, b, o;
        a.v = *(const bf16x8*)((const bf16s*)sd.p0 + r0o);
        b.v = *(const bf16x8*)((const bf16s*)sd.p1 + r1o);
#pragma unroll
        for (int j = 0; j < 8; ++j)
          o.h[j] = __float2bfloat16(__bfloat162float(a.h[j]) + __bfloat162float(b.h[j]));
        *(bf16x8*)(lA + (size_t)(i * 256 + tid) * 8) = o.v;
      }
    }
#pragma unroll
    for (int i = 0; i < BN / 32; ++i)
      async_copy16(lB + (size_t)(i * 256 + tid) * 8,
                   W + (size_t)(i * 32 + ra) * 384 + ks * 64 + cs);
    __syncthreads();
#pragma unroll
    for (int kss = 0; kss < 2; ++kss) {
      const int rk = kss ? rk1 : rk0;
      bf16x8 av[4], bv[BN / 32];
#pragma unroll
      for (int f = 0; f < 4; ++f)
        av[f] = *(const bf16x8*)(lA + (size_t)(wm + f * 16 + (lane & 15)) * 64 + rk);
#pragma unroll
      for (int f = 0; f < BN / 32; ++f)
        bv[f] = *(const bf16x8*)(lB + (size_t)(wn + f * 16 + (lane & 15)) * 64 + rk);
#pragma unroll
      for (int i = 0; i < 4; ++i)
#pragma unroll
        for (int j = 0; j < BN / 32; ++j)
          acc[i][j] = __builtin_amdgcn_mfma_f32_16x16x32_bf16(av[i], bv[j], acc[i][j], 0, 0, 0);
    }
    __syncthreads();
  }
}

// ---------------- gate / cand tiles ----------------
struct LayerG {
  Slots6 sl; const bf16s* W; const float* bias;
  const float* h; bf16s* zh; bf16s* zhT; float* r;
};
__device__ __forceinline__ void gate_tile(const LayerG& L, int m0, bf16s* lA, bf16s* lB)
{
  f32x4 acc[4][4];
  small_core<128>(L.sl, m0, L.W, lA, lB, acc);
  const int lane = threadIdx.x & 63, wave = threadIdx.x >> 6;
  const int wm = (wave >> 1) * 64, wn = (wave & 1) * 64;
  const int rq = (lane >> 4) * 4, cl = lane & 15;
#pragma unroll
  for (int fm = 0; fm < 4; ++fm)
#pragma unroll
    for (int fn = 0; fn < 4; ++fn) {
      const int o = wn + fn * 16 + cl;
      const float bias = L.bias[o];
#pragma unroll
      for (int q = 0; q < 4; ++q) {
        size_t gm = (size_t)m0 + wm + fm * 16 + rq + q;
        float s = 1.f / (1.f + expf(-(acc[fm][fn][q] + bias)));
        if (o < 64) {
          float zh = s * L.h[gm * 64 + o];
          L.zh[gm * 64 + o] = __float2bfloat16(zh);
          L.zhT[((size_t)((gm >> 11) * 64 + o)) * 2048 + (gm & 2047)] = __float2bfloat16(zh);
        } else {
          L.r[gm * 64 + (o - 64)] = s;
        }
      }
    }
}

struct LayerC {
  Slots6 sl; const bf16s* W; const float* bias;
  const float* r; float* h32; bf16s* hT; bf16s* h_bf; float* hid;
  bf16s* x1; float* outC; const float* x0; int t;
};
__device__ __forceinline__ void cand_tile(const LayerC& L, int m0, bf16s* lA, bf16s* lB)
{
  f32x4 acc[4][2];
  small_core<64>(L.sl, m0, L.W, lA, lB, acc);
  const int lane = threadIdx.x & 63, wave = threadIdx.x >> 6;
  const int wm = (wave >> 1) * 64, wn = (wave & 1) * 32;
  const int rq = (lane >> 4) * 4, cl = lane & 15;
#pragma unroll
  for (int fm = 0; fm < 4; ++fm)
#pragma unroll
    for (int fn = 0; fn < 2; ++fn) {
      const int d = wn + fn * 16 + cl;
      const float bias = L.bias[d];
#pragma unroll
      for (int q = 0; q < 4; ++q) {
        size_t gm = (size_t)m0 + wm + fm * 16 + rq + q;
        float hc = tanhf(acc[fm][fn][q] + bias);
        float r = L.r[gm * 64 + d];
        float h = L.h32[gm * 64 + d];
        float hn = r * h + (1.f - r) * hc;
        L.h32[gm * 64 + d] = hn;
        int b = (int)(gm >> 11), n = (int)(gm & 2047);
        L.hT[((size_t)(b * 64 + d)) * 2048 + n] = __float2bfloat16(hn);
        L.h_bf[gm * 64 + d] = __float2bfloat16(hn);
        size_t xi = (((size_t)b * kT + L.t) * 2048 + n) * 64 + d;
        if (L.x1) L.x1[gm * 64 + d] = __float2bfloat16(L.x0[xi] + hn);
        if (L.outC) L.outC[xi] = L.x0[xi] + hn;
        if (L.hid) L.hid[gm * 64 + d] = hn;
      }
    }
}

__device__ __forceinline__ Slot Sb_d(const void* p0, int astr, int trow) {
  return Slot{p0, nullptr, astr, trow, 0, 0, 0};
}
__device__ __forceinline__ Slot Sf_d(const void* p0, int astr, int trow) {
  return Slot{p0, nullptr, astr, trow, 0, 0, 1};
}
__device__ __forceinline__ Slot S2_d(const void* p0, const void* p1, int astr1, int trow1) {
  return Slot{p0, p1, 2048, 0, astr1, trow1, 2};
}

// =============== persistent superstep kernel: 512 blocks x 256 thr ===============
struct SuperP {
  const bf16s *A, *A2, *AxF, *A2xF;
  const float *x;
  const bf16s *WgT, *WuT; const float *bg, *bu;
  float *h32_0, *h32_1, *r32_0, *r32_1;
  bf16s *hT0, *hT1, *hbf0, *hbf1;
  bf16s *zhT0, *zhT1, *zhbf0, *zhbf1;
  bf16s *x1b;
  bf16s *sAh0, *sA2h0, *sAh1, *sA2h1, *sZ0, *sA2Z0, *sZ1, *sA2Z1;
  float *outCur, *outHid;
  unsigned *bar;
};

__device__ __forceinline__ int swz_tile512(int b) {
  return ((b & 7) << 6) | (b >> 3);   // XCD-chunked bijection on [0,512)
}

__global__ __launch_bounds__(256, 2) void k_super(SuperP P)
{
  __shared__ bf16s lA[128 * 64];
  __shared__ bf16s lB[128 * 64];
  const int bid = blockIdx.x;
  const unsigned nb = gridDim.x;
  int g = 0;   // global stage index

  const int v = swz_tile512(bid);
  const int dg = v >> 8;                 // diffusion group (layer)
  const int dt = v & 255;
  const int dsp = dt >> 7;               // support select (A / A2)
  const int dm0 = ((dt >> 3) & 15) * 128;
  const int dc0 = (dt & 7) * 128;
  const bool isA = bid < 256;            // gate/cand layer select
  const int gm0 = (bid & 255) * 128;

  for (int s = 0; s <= kT; ++s) {
    const bool aA = (s < kT), aB = (s >= 1);
    const int tA = s, tB = s - 1;
    bf16s* x1cur  = P.x1b + (size_t)(s & 1) * kBND;
    bf16s* x1prev = P.x1b + (size_t)((s - 1) & 1) * kBND;

    // ---- phase 0: diffuse h0 (always) and h1 (if aB) ----
    if (dg == 0 || aB) {
      const bf16s* S = dsp ? P.A2 : P.A;
      const bf16s* src = dg ? P.hT1 : P.hT0;
      bf16s* out = dg ? (dsp ? P.sA2h1 : P.sAh1) : (dsp ? P.sA2h0 : P.sAh0);
      diff_tile(S, src, out, dm0, dc0, lA, lB);
    }
    grid_bar(P.bar, g++, nb);

    // ---- gate ----
    if (isA ? aA : aB) {
      LayerG L;
      if (isA) {
        L.sl.s[0] = Sf_d(P.x, kT * 2048, tA * 2048);
        L.sl.s[1] = Sb_d(P.hbf0, 2048, 0);
        L.sl.s[2] = Sb_d(P.AxF, kT * 2048, tA * 2048);
        L.sl.s[3] = Sb_d(P.sAh0, 2048, 0);
        L.sl.s[4] = Sb_d(P.A2xF, kT * 2048, tA * 2048);
        L.sl.s[5] = Sb_d(P.sA2h0, 2048, 0);
        L.W = P.WgT; L.bias = P.bg; L.h = P.h32_0;
        L.zh = P.zhbf0; L.zhT = P.zhT0; L.r = P.r32_0;
      } else {
        L.sl.s[0] = Sb_d(x1prev, 2048, 0);
        L.sl.s[1] = Sb_d(P.hbf1, 2048, 0);
        L.sl.s[2] = S2_d(P.sAh0, P.AxF, kT * 2048, tB * 2048);   // A@x1 = A@h0 + A@x
        L.sl.s[3] = Sb_d(P.sAh1, 2048, 0);
        L.sl.s[4] = S2_d(P.sA2h0, P.A2xF, kT * 2048, tB * 2048);
        L.sl.s[5] = Sb_d(P.sA2h1, 2048, 0);
        L.W = P.WgT + (size_t)128 * 384; L.bias = P.bg + 128; L.h = P.h32_1;
        L.zh = P.zhbf1; L.zhT = P.zhT1; L.r = P.r32_1;
      }
      gate_tile(L, gm0, lA, lB);
    }
    grid_bar(P.bar, g++, nb);

    // ---- phase 1: diffuse zh0 (aA) / zh1 (aB) ----
    if (dg ? aB : aA) {
      const bf16s* S = dsp ? P.A2 : P.A;
      const bf16s* src = dg ? P.zhT1 : P.zhT0;
      bf16s* out = dg ? (dsp ? P.sA2Z1 : P.sZ1) : (dsp ? P.sA2Z0 : P.sZ0);
      diff_tile(S, src, out, dm0, dc0, lA, lB);
    }
    grid_bar(P.bar, g++, nb);

    // ---- candidate + GRU update ----
    if (isA ? aA : aB) {
      LayerC L;
      if (isA) {
        L.sl.s[0] = Sf_d(P.x, kT * 2048, tA * 2048);
        L.sl.s[1] = Sb_d(P.zhbf0, 2048, 0);
        L.sl.s[2] = Sb_d(P.AxF, kT * 2048, tA * 2048);
        L.sl.s[3] = Sb_d(P.sZ0, 2048, 0);
        L.sl.s[4] = Sb_d(P.A2xF, kT * 2048, tA * 2048);
        L.sl.s[5] = Sb_d(P.sA2Z0, 2048, 0);
        L.W = P.WuT; L.bias = P.bu; L.r = P.r32_0; L.h32 = P.h32_0;
        L.hT = P.hT0; L.h_bf = P.hbf0;
        L.hid = (tA == kT - 1) ? P.outHid : nullptr;
        L.x1 = x1cur; L.outC = nullptr; L.x0 = P.x; L.t = tA;
      } else {
        L.sl.s[0] = Sb_d(x1prev, 2048, 0);
        L.sl.s[1] = Sb_d(P.zhbf1, 2048, 0);
        L.sl.s[2] = S2_d(P.sAh0, P.AxF, kT * 2048, tB * 2048);
        L.sl.s[3] = Sb_d(P.sZ1, 2048, 0);
        L.sl.s[4] = S2_d(P.sA2h0, P.A2xF, kT * 2048, tB * 2048);
        L.sl.s[5] = Sb_d(P.sA2Z1, 2048, 0);
        L.W = P.WuT + (size_t)64 * 384; L.bias = P.bu + 64; L.r = P.r32_1; L.h32 = P.h32_1;
        L.hT = P.hT1; L.h_bf = P.hbf1;
        L.hid = (tB == kT - 1) ? P.outHid + kBND : nullptr;
        L.x1 = nullptr; L.outC = P.outCur; L.x0 = P.x; L.t = tB;
      }
      cand_tile(L, gm0, lA, lB);
    }
    grid_bar(P.bar, g++, nb);
  }
}

// ---------------- utility kernels ----------------
__global__ __launch_bounds__(256) void transpose_cvt(
    const float* in, bf16s* out, int nrows, int ncols,
    size_t in_ostride, size_t out_ostride)
{
  __shared__ float tile[64][65];
  const int r0 = blockIdx.x * 64, c0 = blockIdx.y * 64;
  in  += (size_t)blockIdx.z * in_ostride;
  out += (size_t)blockIdx.z * out_ostride;
  const int tx = threadIdx.x & 63, ty = threadIdx.x >> 6;
#pragma unroll
  for (int i = 0; i < 64; i += 4)
    tile[ty + i][tx] = in[(size_t)(r0 + ty + i) * ncols + c0 + tx];
  __syncthreads();
#pragma unroll
  for (int i = 0; i < 64; i += 4)
    out[(size_t)(c0 + ty + i) * nrows + r0 + tx] = __float2bfloat16(tile[tx][ty + i]);
}

__global__ __launch_bounds__(256) void k_cvt(const float* in, bf16s* out, int n)
{
  int i = blockIdx.x * 256 + threadIdx.x;
  if (i < n) out[i] = __float2bfloat16(in[i]);
}

__global__ __launch_bounds__(256) void k_repack(
    const float* Wg, const float* Wu, bf16s* WgT, bf16s* WuT)
{
  int idx = blockIdx.x * 256 + threadIdx.x;
  if (idx < 2 * 3 * 128 * 128) {
    int o = idx & 127, cin = (idx >> 7) & 127, k = (idx >> 14) % 3, l = idx / 49152;
    WgT[((size_t)(l * 128 + o)) * 384 + (2 * k + (cin >> 6)) * 64 + (cin & 63)] =
        __float2bfloat16(Wg[idx]);
  }
  if (idx < 2 * 3 * 128 * 64) {
    int o = idx & 63, cin = (idx >> 6) & 127, k = (idx >> 13) % 3, l = idx / 24576;
    WuT[((size_t)(l * 64 + o)) * 384 + (2 * k + (cin >> 6)) * 64 + (cin & 63)] =
        __float2bfloat16(Wu[idx]);
  }
}

__global__ __launch_bounds__(256) void init_layer(
    const float* ist_l, float* h32, bf16s* hT, bf16s* h_bf)
{
  size_t idx = (size_t)blockIdx.x * 256 + threadIdx.x;
  if (idx >= kBND) return;
  int d = (int)(idx & 63);
  size_t row = idx >> 6;
  int n = (int)(row & 2047), b = (int)(row >> 11);
  float h = ist_l[idx];
  h32[idx] = h;
  hT[((size_t)(b * 64 + d)) * 2048 + n] = __float2bfloat16(h);
  h_bf[idx] = __float2bfloat16(h);
}

// ---------------- host orchestration ----------------
extern "C" void kernel_launch(void* const* d_in, const int* in_sizes, int n_in,
                              void* d_out, int out_size, void* d_ws, size_t ws_size,
                              hipStream_t stream)
{
  (void)in_sizes; (void)n_in; (void)out_size; (void)ws_size;
  const float* x   = (const float*)d_in[0];
  const float* ist = (const float*)d_in[1];
  const float* adj = (const float*)d_in[2];
  const float* Wg  = (const float*)d_in[3];
  const float* bg  = (const float*)d_in[4];
  const float* Wu  = (const float*)d_in[5];
  const float* bu  = (const float*)d_in[6];
  float* outCur = (float*)d_out;
  float* outHid = outCur + (size_t)kB * kT * kN * kD;

  char* p = (char*)d_ws;
  auto carve = [&](size_t bytes) { char* q = p; p += (bytes + 255) & ~(size_t)255; return q; };
  const size_t barBytes = (size_t)(kNSTG * 8 + kNSTG) * 128;   // arrival slots + release flags
  unsigned* bar = (unsigned*)carve(barBytes);
  bf16s* A_bf  = (bf16s*)carve((size_t)2048 * 2048 * 2);
  bf16s* A2_bf = (bf16s*)carve((size_t)2048 * 2048 * 2);
  bf16s* WgT   = (bf16s*)carve((size_t)2 * 128 * 384 * 2);
  bf16s* WuT   = (bf16s*)carve((size_t)2 * 64 * 384 * 2);
  float* h32b  = (float*)carve(2 * kBND * 4);
  float* r32b  = (float*)carve(2 * kBND * 4);
  bf16s* hTb   = (bf16s*)carve(2 * kBND * 2);
  bf16s* hbfb  = (bf16s*)carve(2 * kBND * 2);
  bf16s* zhTb  = (bf16s*)carve(2 * kBND * 2);
  bf16s* zhbfb = (bf16s*)carve(2 * kBND * 2);
  bf16s* x1b   = (bf16s*)carve(2 * kBND * 2);
  bf16s* sAh0  = (bf16s*)carve(kBND * 2);
  bf16s* sA2h0 = (bf16s*)carve(kBND * 2);
  bf16s* sAh1  = (bf16s*)carve(kBND * 2);
  bf16s* sA2h1 = (bf16s*)carve(kBND * 2);
  bf16s* sZ0   = (bf16s*)carve(kBND * 2);
  bf16s* sA2Z0 = (bf16s*)carve(kBND * 2);
  bf16s* sZ1   = (bf16s*)carve(kBND * 2);
  bf16s* sA2Z1 = (bf16s*)carve(kBND * 2);
  const size_t xTfull = (size_t)kB * kT * kD * kN * 2;   // 96 MiB
  bf16s* AxF  = (bf16s*)carve(xTfull);
  bf16s* A2xF = (bf16s*)carve(xTfull);
  bf16s* xTh  = (bf16s*)carve(xTfull / 2);
  bf16s* AT_bf = AxF;   // alias: AT dead (after k_a2) before AxF is written

  // ---- setup ----
  hipMemsetAsync(bar, 0, barBytes, stream);
  k_cvt<<<dim3((2048 * 2048 + 255) / 256), 256, 0, stream>>>(adj, A_bf, 2048 * 2048);
  transpose_cvt<<<dim3(32, 32, 1), 256, 0, stream>>>(adj, AT_bf, 2048, 2048, 0, 0);
  k_a2<<<dim3(16, 16, 1), 256, 0, stream>>>(A_bf, AT_bf, A2_bf);
  k_repack<<<dim3(384), 256, 0, stream>>>(Wg, Wu, WgT, WuT);
  init_layer<<<dim3((int)(kBND / 256)), 256, 0, stream>>>(ist, h32b, hTb, hbfb);
  init_layer<<<dim3((int)(kBND / 256)), 256, 0, stream>>>(ist + kBND, h32b + kBND, hTb + kBND, hbfb + kBND);

  // ---- batched layer-0 x-diffusion (two b-halves) ----
  for (int h = 0; h < 2; ++h) {
    size_t off = (size_t)h * 8 * kT * 131072;
    transpose_cvt<<<dim3(32, 1, 8 * kT), 256, 0, stream>>>(x + off, xTh, 2048, 64, 131072, 131072);
    DiffP dp; dp.S0 = A_bf; dp.S1 = A2_bf; dp.colsPerGrp = 12288;
    dp.g[0] = DiffGrp{xTh, AxF + off, A2xF + off};
    dp.g[1] = dp.g[2] = dp.g[3] = DiffGrp{nullptr, nullptr, nullptr};
    k_diff<<<dim3(32, 96), 256, 0, stream>>>(dp);
  }

  // ---- persistent superstep loop (plain launch, split-counter barrier) ----
  SuperP P;
  P.A = A_bf; P.A2 = A2_bf; P.AxF = AxF; P.A2xF = A2xF;
  P.x = x; P.WgT = WgT; P.WuT = WuT; P.bg = bg; P.bu = bu;
  P.h32_0 = h32b; P.h32_1 = h32b + kBND;
  P.r32_0 = r32b; P.r32_1 = r32b + kBND;
  P.hT0 = hTb; P.hT1 = hTb + kBND;
  P.hbf0 = hbfb; P.hbf1 = hbfb + kBND;
  P.zhT0 = zhTb; P.zhT1 = zhTb + kBND;
  P.zhbf0 = zhbfb; P.zhbf1 = zhbfb + kBND;
  P.x1b = x1b;
  P.sAh0 = sAh0; P.sA2h0 = sA2h0; P.sAh1 = sAh1; P.sA2h1 = sA2h1;
  P.sZ0 = sZ0; P.sA2Z0 = sA2Z0; P.sZ1 = sZ1; P.sA2Z1 = sA2Z1;
  P.outCur = outCur; P.outHid = outHid;
  P.bar = bar;
  k_super<<<dim3(512), dim3(256), 0, stream>>>(P);
}

// Round 10
// 4764.160 us; speedup vs baseline: 2.4508x; 1.8366x over previous
//
#include <hip/hip_runtime.h>
#include <hip/hip_bf16.h>
#include <math.h>

typedef __bf16 bf16x8 __attribute__((ext_vector_type(8)));
typedef float f32x4 __attribute__((ext_vector_type(4)));
typedef __hip_bfloat16 bf16s;

constexpr int kB = 16, kT = 24, kN = 2048, kD = 64;
constexpr size_t kBND = (size_t)kB * kN * kD;  // 2097152

// slot types: 0 = bf16 direct (global_load_lds), 1 = f32 (cvt), 2 = bf16+bf16 add
struct Slot { const void* p0; const void* p1; int astr0, trow0, astr1, trow1, type; };
struct Slots6 { Slot s[6]; };
struct DiffGrp { const bf16s* src; bf16s* oA; bf16s* oA2; };
struct DiffP { const bf16s* S0; const bf16s* S1; DiffGrp g[4]; int colsPerGrp; };

__device__ __forceinline__ void async_copy16(void* lds, const void* g) {
  __builtin_amdgcn_global_load_lds((const __attribute__((address_space(1))) void*)g,
                                   (__attribute__((address_space(3))) void*)lds,
                                   16, 0, 0);
}

// LDS tiles [rows][64] bf16 staged linearly; XOR swizzle on 16B chunks:
// source chunk (tid&7)^(row&7), read chunk g^(row&7). 0 conflicts (r3).
// r4: 256-thr/32KB/2 blocks-per-CU is the proven shape.
// r7-r9: grid barriers (cg, single-counter, split-counter) all cost ~60-85us
// (device-fence = per-XCD L2 wb+inv + L3 refetch) -> persistent kernels lose
// to multi-launch. r10: fuse phase-1 diff into cand (no cross-block dep).

// ---------------- diffusion core (r5, proven) ----------------
__device__ __forceinline__ void diff_core(
    const bf16s* __restrict__ S, const bf16s* __restrict__ Bsrc,
    int m0, int c0, bf16s* lA, bf16s* lB, f32x4 (&acc)[4][4])
{
  const int tid = threadIdx.x, lane = tid & 63, wave = tid >> 6;
  const int wm = (wave >> 1) * 64, wn = (wave & 1) * 64;
  const f32x4 zero = {0.f, 0.f, 0.f, 0.f};
#pragma unroll
  for (int i = 0; i < 4; ++i)
#pragma unroll
    for (int j = 0; j < 4; ++j) acc[i][j] = zero;

  const int ra = tid >> 3;
  const int cs = ((tid & 7) ^ (ra & 7)) * 8;
  const int rk0 = ((lane >> 4) ^ (lane & 7)) * 8;
  const int rk1 = ((4 + (lane >> 4)) ^ (lane & 7)) * 8;

  for (int k0 = 0; k0 < 2048; k0 += 64) {
#pragma unroll
    for (int i = 0; i < 4; ++i) {
      async_copy16(lA + (size_t)(i * 256 + tid) * 8,
                   S + (size_t)(m0 + i * 32 + ra) * 2048 + k0 + cs);
      async_copy16(lB + (size_t)(i * 256 + tid) * 8,
                   Bsrc + (size_t)(c0 + i * 32 + ra) * 2048 + k0 + cs);
    }
    __syncthreads();
#pragma unroll
    for (int ks = 0; ks < 2; ++ks) {
      const int rk = ks ? rk1 : rk0;
      bf16x8 av[4], bv[4];
#pragma unroll
      for (int f = 0; f < 4; ++f) {
        av[f] = *(const bf16x8*)(lA + (size_t)(wm + f * 16 + (lane & 15)) * 64 + rk);
        bv[f] = *(const bf16x8*)(lB + (size_t)(wn + f * 16 + (lane & 15)) * 64 + rk);
      }
#pragma unroll
      for (int i = 0; i < 4; ++i)
#pragma unroll
        for (int j = 0; j < 4; ++j)
          acc[i][j] = __builtin_amdgcn_mfma_f32_16x16x32_bf16(av[i], bv[j], acc[i][j], 0, 0, 0);
    }
    __syncthreads();
  }
}

__device__ __forceinline__ void diff_tile(
    const bf16s* __restrict__ S, const bf16s* __restrict__ src, bf16s* out,
    int m0, int c0, bf16s* lA, bf16s* lB)
{
  f32x4 acc[4][4];
  diff_core(S, src, m0, c0, lA, lB, acc);
  const int lane = threadIdx.x & 63, wave = threadIdx.x >> 6;
  const int wm = (wave >> 1) * 64, wn = (wave & 1) * 64;
  const int rq = (lane >> 4) * 4, cl = lane & 15;
#pragma unroll
  for (int fm = 0; fm < 4; ++fm)
#pragma unroll
    for (int fn = 0; fn < 4; ++fn)
#pragma unroll
      for (int q = 0; q < 4; ++q) {
        int gm = m0 + wm + fm * 16 + rq + q;
        int gc = c0 + wn + fn * 16 + cl;
        size_t off = ((size_t)(gc >> 6) * 2048 + gm) * 64 + (gc & 63);
        out[off] = __float2bfloat16(acc[fm][fn][q]);
      }
}

// ---------------- diffusion kernel (prologue + per-step phase-0) ----------------
__global__ __launch_bounds__(256) void k_diff(DiffP p)
{
  __shared__ bf16s lA[128 * 64];
  __shared__ bf16s lB[128 * 64];
  const int mi = blockIdx.x;
  const bf16s* S = (mi >> 4) ? p.S1 : p.S0;
  const int m0 = (mi & 15) * 128;
  const int ybpg = p.colsPerGrp >> 7;
  const int grp = blockIdx.y / ybpg;
  const int c0 = (blockIdx.y - grp * ybpg) * 128;
  const DiffGrp G = p.g[grp];
  bf16s* out = (mi >> 4) ? G.oA2 : G.oA;
  diff_tile(S, G.src, out, m0, c0, lA, lB);
}

// ---------------- setup: A2 = 2*A@A - I ----------------
__global__ __launch_bounds__(256) void k_a2(
    const bf16s* __restrict__ A, const bf16s* __restrict__ AT, bf16s* A2)
{
  __shared__ bf16s lA[128 * 64];
  __shared__ bf16s lB[128 * 64];
  const int m0 = blockIdx.x * 128, n0 = blockIdx.y * 128;
  f32x4 acc[4][4];
  diff_core(A, AT, m0, n0, lA, lB, acc);
  const int lane = threadIdx.x & 63, wave = threadIdx.x >> 6;
  const int wm = (wave >> 1) * 64, wn = (wave & 1) * 64;
  const int rq = (lane >> 4) * 4, cl = lane & 15;
#pragma unroll
  for (int fm = 0; fm < 4; ++fm)
#pragma unroll
    for (int fn = 0; fn < 4; ++fn)
#pragma unroll
      for (int q = 0; q < 4; ++q) {
        int gm = m0 + wm + fm * 16 + rq + q;
        int gc = n0 + wn + fn * 16 + cl;
        A2[(size_t)gm * 2048 + gc] = __float2bfloat16(2.f * acc[fm][fn][q] - (gm == gc ? 1.f : 0.f));
      }
}

// =============== small GEMM core (gate): 128 contiguous rows, K = 6x64 ===============
template<int BN>
__device__ __forceinline__ void small_core(
    const Slots6& sl, int m0, const bf16s* __restrict__ W,
    bf16s* lA, bf16s* lB, f32x4 (&acc)[4][BN / 32])
{
  const int tid = threadIdx.x, lane = tid & 63, wave = tid >> 6;
  const int wm = (wave >> 1) * 64, wn = (wave & 1) * (BN / 2);
  const f32x4 zero = {0.f, 0.f, 0.f, 0.f};
#pragma unroll
  for (int i = 0; i < 4; ++i)
#pragma unroll
    for (int j = 0; j < BN / 32; ++j) acc[i][j] = zero;

  const int ra = tid >> 3;
  const int cs = ((tid & 7) ^ (ra & 7)) * 8;
  const int rk0 = ((lane >> 4) ^ (lane & 7)) * 8;
  const int rk1 = ((4 + (lane >> 4)) ^ (lane & 7)) * 8;

#pragma unroll
  for (int ks = 0; ks < 6; ++ks) {
    const Slot sd = sl.s[ks];
    if (sd.type == 0) {
      const bf16s* base = (const bf16s*)sd.p0;
#pragma unroll
      for (int i = 0; i < 4; ++i) {
        int row = m0 + i * 32 + ra;
        size_t roff = ((size_t)(row >> 11) * sd.astr0 + sd.trow0 + (row & 2047)) * 64 + cs;
        async_copy16(lA + (size_t)(i * 256 + tid) * 8, base + roff);
      }
    } else if (sd.type == 1) {
#pragma unroll
      for (int i = 0; i < 4; ++i) {
        int row = m0 + i * 32 + ra;
        size_t roff = ((size_t)(row >> 11) * sd.astr0 + sd.trow0 + (row & 2047)) * 64 + cs;
        const float4* q0 = (const float4*)((const float*)sd.p0 + roff);
        float4 a = q0[0], b = q0[1];
        union { bf16x8 v; bf16s h[8]; } u;
        u.h[0] = __float2bfloat16(a.x); u.h[1] = __float2bfloat16(a.y);
        u.h[2] = __float2bfloat16(a.z); u.h[3] = __float2bfloat16(a.w);
        u.h[4] = __float2bfloat16(b.x); u.h[5] = __float2bfloat16(b.y);
        u.h[6] = __float2bfloat16(b.z); u.h[7] = __float2bfloat16(b.w);
        *(bf16x8*)(lA + (size_t)(i * 256 + tid) * 8) = u.v;
      }
    } else {
#pragma unroll
      for (int i = 0; i < 4; ++i) {
        int row = m0 + i * 32 + ra;
        size_t r0o = ((size_t)(row >> 11) * sd.astr0 + sd.trow0 + (row & 2047)) * 64 + cs;
        size_t r1o = ((size_t)(row >> 11) * sd.astr1 + sd.trow1 + (row & 2047)) * 64 + cs;
        union { bf16x8 v; bf16s h[8]; } a, b, o;
        a.v = *(const bf16x8*)((const bf16s*)sd.p0 + r0o);
        b.v = *(const bf16x8*)((const bf16s*)sd.p1 + r1o);
#pragma unroll
        for (int j = 0; j < 8; ++j)
          o.h[j] = __float2bfloat16(__bfloat162float(a.h[j]) + __bfloat162float(b.h[j]));
        *(bf16x8*)(lA + (size_t)(i * 256 + tid) * 8) = o.v;
      }
    }
#pragma unroll
    for (int i = 0; i < BN / 32; ++i)
      async_copy16(lB + (size_t)(i * 256 + tid) * 8,
                   W + (size_t)(i * 32 + ra) * 384 + ks * 64 + cs);
    __syncthreads();
#pragma unroll
    for (int kss = 0; kss < 2; ++kss) {
      const int rk = kss ? rk1 : rk0;
      bf16x8 av[4], bv[BN / 32];
#pragma unroll
      for (int f = 0; f < 4; ++f)
        av[f] = *(const bf16x8*)(lA + (size_t)(wm + f * 16 + (lane & 15)) * 64 + rk);
#pragma unroll
      for (int f = 0; f < BN / 32; ++f)
        bv[f] = *(const bf16x8*)(lB + (size_t)(wn + f * 16 + (lane & 15)) * 64 + rk);
#pragma unroll
      for (int i = 0; i < 4; ++i)
#pragma unroll
        for (int j = 0; j < BN / 32; ++j)
          acc[i][j] = __builtin_amdgcn_mfma_f32_16x16x32_bf16(av[i], bv[j], acc[i][j], 0, 0, 0);
    }
    __syncthreads();
  }
}

// ---------------- gate kernel (unchanged from r5) ----------------
struct LayerG {
  Slots6 sl; const bf16s* W; const float* bias;
  const float* h; bf16s* zh; bf16s* zhT; float* r;
};
__global__ __launch_bounds__(256) void k_gate(LayerG A, LayerG B, int nA)
{
  __shared__ bf16s lA[128 * 64];
  __shared__ bf16s lB[128 * 64];
  const int bx = blockIdx.x;
  const bool isA = bx < nA;
  const LayerG L = isA ? A : B;
  const int m0 = (isA ? bx : bx - nA) * 128;
  f32x4 acc[4][4];
  small_core<128>(L.sl, m0, L.W, lA, lB, acc);
  const int lane = threadIdx.x & 63, wave = threadIdx.x >> 6;
  const int wm = (wave >> 1) * 64, wn = (wave & 1) * 64;
  const int rq = (lane >> 4) * 4, cl = lane & 15;
#pragma unroll
  for (int fm = 0; fm < 4; ++fm)
#pragma unroll
    for (int fn = 0; fn < 4; ++fn) {
      const int o = wn + fn * 16 + cl;
      const float bias = L.bias[o];
#pragma unroll
      for (int q = 0; q < 4; ++q) {
        size_t gm = (size_t)m0 + wm + fm * 16 + rq + q;
        float s = 1.f / (1.f + expf(-(acc[fm][fn][q] + bias)));
        if (o < 64) {
          float zh = s * L.h[gm * 64 + o];
          L.zh[gm * 64 + o] = __float2bfloat16(zh);
          L.zhT[((size_t)((gm >> 11) * 64 + o)) * 2048 + (gm & 2047)] = __float2bfloat16(zh);
        } else {
          L.r[gm * 64 + (o - 64)] = s;
        }
      }
    }
}

__device__ __forceinline__ Slot Sb_d(const void* p0, int astr, int trow) {
  return Slot{p0, nullptr, astr, trow, 0, 0, 0};
}
__device__ __forceinline__ Slot Sf_d(const void* p0, int astr, int trow) {
  return Slot{p0, nullptr, astr, trow, 0, 0, 1};
}
__device__ __forceinline__ Slot S2_d(const void* p0, const void* p1, int astr1, int trow1) {
  return Slot{p0, p1, 2048, 0, astr1, trow1, 2};
}

// =============== fused zh-diffusion + candidate kernel ===============
// 512 blocks x 256 thr. Block = (layer, mb in [0,32), cb in [0,8)):
// diffuses zh tile [64 n x 128 c] for BOTH supports (LDS: SA 8K | SA2 8K | B 16K),
// writes slabs, then runs the cand GEMM for exactly its own 128 rows
// (b-pair x 64 n) reading the slabs it just wrote (same-block, L2-hot).
struct CandP {
  const bf16s *A, *A2;
  const bf16s *zhT0, *zhT1;
  bf16s *sZ0, *sA2Z0, *sZ1, *sA2Z1;
  const float *x;
  const bf16s *zhbf0, *zhbf1, *x1prev;
  const bf16s *AxF, *A2xF, *sAh0, *sA2h0;
  const bf16s *WuT; const float *bu;
  const float *r32_0, *r32_1;
  float *h32_0, *h32_1;
  bf16s *hT0, *hT1, *hbf0, *hbf1;
  bf16s *x1cur;
  float *outCur, *outHid;
  int tA, tB, aA, aB;
};

__global__ __launch_bounds__(256, 2) void k_dcand(CandP P)
{
  __shared__ bf16s lds[16384];   // 32KB
  const int layer = blockIdx.x >> 8;
  if (layer ? !P.aB : !P.aA) return;
  const int lin = blockIdx.x & 255;
  // XCD key = mb%8 so blocks sharing an A/A2 row-panel land on one XCD L2
  const int mb = (lin & 7) | (((lin >> 6) & 3) << 3);
  const int cb = (lin >> 3) & 7;
  const int m0 = mb * 64, c0 = cb * 128, b0 = cb * 2;
  const int t = layer ? P.tB : P.tA;

  const int tid = threadIdx.x, lane = tid & 63, wave = tid >> 6;
  const int ra = tid >> 3;
  const int cs = ((tid & 7) ^ (ra & 7)) * 8;
  const int rk0 = ((lane >> 4) ^ (lane & 7)) * 8;
  const int rk1 = ((4 + (lane >> 4)) ^ (lane & 7)) * 8;

  // ---- fused diffusion: C[64 x 128] = {A, A2} @ zh^T ----
  {
    bf16s* lA  = lds;           // 64x64
    bf16s* lA2 = lds + 4096;    // 64x64
    bf16s* lB  = lds + 8192;    // 128x64
    const int wm = (wave >> 1) * 32, wn = (wave & 1) * 64;
    const bf16s* src = layer ? P.zhT1 : P.zhT0;

    f32x4 acc[2][2][4];
    const f32x4 zero = {0.f, 0.f, 0.f, 0.f};
#pragma unroll
    for (int s = 0; s < 2; ++s)
#pragma unroll
      for (int i = 0; i < 2; ++i)
#pragma unroll
        for (int j = 0; j < 4; ++j) acc[s][i][j] = zero;

    for (int k0 = 0; k0 < 2048; k0 += 64) {
#pragma unroll
      for (int i = 0; i < 2; ++i) {
        async_copy16(lA  + (size_t)(i * 256 + tid) * 8,
                     P.A  + (size_t)(m0 + i * 32 + ra) * 2048 + k0 + cs);
        async_copy16(lA2 + (size_t)(i * 256 + tid) * 8,
                     P.A2 + (size_t)(m0 + i * 32 + ra) * 2048 + k0 + cs);
      }
#pragma unroll
      for (int i = 0; i < 4; ++i)
        async_copy16(lB + (size_t)(i * 256 + tid) * 8,
                     src + (size_t)(c0 + i * 32 + ra) * 2048 + k0 + cs);
      __syncthreads();
#pragma unroll
      for (int ks = 0; ks < 2; ++ks) {
        const int rk = ks ? rk1 : rk0;
        bf16x8 av0[2], av1[2], bv[4];
#pragma unroll
        for (int f = 0; f < 2; ++f) {
          av0[f] = *(const bf16x8*)(lA  + (size_t)(wm + f * 16 + (lane & 15)) * 64 + rk);
          av1[f] = *(const bf16x8*)(lA2 + (size_t)(wm + f * 16 + (lane & 15)) * 64 + rk);
        }
#pragma unroll
        for (int f = 0; f < 4; ++f)
          bv[f] = *(const bf16x8*)(lB + (size_t)(wn + f * 16 + (lane & 15)) * 64 + rk);
#pragma unroll
        for (int i = 0; i < 2; ++i)
#pragma unroll
          for (int j = 0; j < 4; ++j) {
            acc[0][i][j] = __builtin_amdgcn_mfma_f32_16x16x32_bf16(av0[i], bv[j], acc[0][i][j], 0, 0, 0);
            acc[1][i][j] = __builtin_amdgcn_mfma_f32_16x16x32_bf16(av1[i], bv[j], acc[1][i][j], 0, 0, 0);
          }
      }
      __syncthreads();
    }

    // slab writes (own cand rows read these back below)
    bf16s* oZ0 = layer ? P.sZ1   : P.sZ0;
    bf16s* oZ1 = layer ? P.sA2Z1 : P.sA2Z0;
    const int rq = (lane >> 4) * 4, cl = lane & 15;
#pragma unroll
    for (int sp = 0; sp < 2; ++sp) {
      bf16s* out = sp ? oZ1 : oZ0;
#pragma unroll
      for (int fm = 0; fm < 2; ++fm)
#pragma unroll
        for (int fn = 0; fn < 4; ++fn)
#pragma unroll
          for (int q = 0; q < 4; ++q) {
            int gm = m0 + wm + fm * 16 + rq + q;
            int gc = c0 + wn + fn * 16 + cl;
            out[((size_t)(gc >> 6) * 2048 + gm) * 64 + (gc & 63)] =
                __float2bfloat16(acc[sp][fm][fn][q]);
          }
    }
  }
  __syncthreads();   // drains slab stores (vmcnt 0) before re-reading

  // ---- candidate GEMM: 128 virtual rows (b-pair x 64 n) x 64 outs ----
  Slots6 sl;
  if (!layer) {
    sl.s[0] = Sf_d(P.x, kT * 2048, P.tA * 2048);
    sl.s[1] = Sb_d(P.zhbf0, 2048, 0);
    sl.s[2] = Sb_d(P.AxF, kT * 2048, P.tA * 2048);
    sl.s[3] = Sb_d(P.sZ0, 2048, 0);
    sl.s[4] = Sb_d(P.A2xF, kT * 2048, P.tA * 2048);
    sl.s[5] = Sb_d(P.sA2Z0, 2048, 0);
  } else {
    sl.s[0] = Sb_d(P.x1prev, 2048, 0);
    sl.s[1] = Sb_d(P.zhbf1, 2048, 0);
    sl.s[2] = S2_d(P.sAh0, P.AxF, kT * 2048, P.tB * 2048);   // A@x1 = A@h0 + A@x
    sl.s[3] = Sb_d(P.sZ1, 2048, 0);
    sl.s[4] = S2_d(P.sA2h0, P.A2xF, kT * 2048, P.tB * 2048);
    sl.s[5] = Sb_d(P.sA2Z1, 2048, 0);
  }
  const bf16s* W = P.WuT + (size_t)layer * 64 * 384;
  const float* bias = P.bu + layer * 64;

  bf16s* gA = lds;          // 128x64
  bf16s* gB = lds + 8192;   // 64x64
  const int wmG = (wave >> 1) * 64, wnG = (wave & 1) * 32;
  f32x4 gacc[4][2];
  const f32x4 zero = {0.f, 0.f, 0.f, 0.f};
#pragma unroll
  for (int i = 0; i < 4; ++i)
#pragma unroll
    for (int j = 0; j < 2; ++j) gacc[i][j] = zero;

#pragma unroll
  for (int ks = 0; ks < 6; ++ks) {
    const Slot sd = sl.s[ks];
    if (sd.type == 0) {
      const bf16s* base = (const bf16s*)sd.p0;
#pragma unroll
      for (int i = 0; i < 4; ++i) {
        int vrow = i * 32 + ra;
        size_t gm = (size_t)(b0 + (vrow >> 6)) * 2048 + m0 + (vrow & 63);
        size_t roff = ((gm >> 11) * sd.astr0 + sd.trow0 + (gm & 2047)) * 64 + cs;
        async_copy16(gA + (size_t)(i * 256 + tid) * 8, base + roff);
      }
    } else if (sd.type == 1) {
#pragma unroll
      for (int i = 0; i < 4; ++i) {
        int vrow = i * 32 + ra;
        size_t gm = (size_t)(b0 + (vrow >> 6)) * 2048 + m0 + (vrow & 63);
        size_t roff = ((gm >> 11) * sd.astr0 + sd.trow0 + (gm & 2047)) * 64 + cs;
        const float4* q0 = (const float4*)((const float*)sd.p0 + roff);
        float4 a = q0[0], b = q0[1];
        union { bf16x8 v; bf16s h[8]; } u;
        u.h[0] = __float2bfloat16(a.x); u.h[1] = __float2bfloat16(a.y);
        u.h[2] = __float2bfloat16(a.z); u.h[3] = __float2bfloat16(a.w);
        u.h[4] = __float2bfloat16(b.x); u.h[5] = __float2bfloat16(b.y);
        u.h[6] = __float2bfloat16(b.z); u.h[7] = __float2bfloat16(b.w);
        *(bf16x8*)(gA + (size_t)(i * 256 + tid) * 8) = u.v;
      }
    } else {
#pragma unroll
      for (int i = 0; i < 4; ++i) {
        int vrow = i * 32 + ra;
        size_t gm = (size_t)(b0 + (vrow >> 6)) * 2048 + m0 + (vrow & 63);
        size_t r0o = ((gm >> 11) * sd.astr0 + sd.trow0 + (gm & 2047)) * 64 + cs;
        size_t r1o = ((gm >> 11) * sd.astr1 + sd.trow1 + (gm & 2047)) * 64 + cs;
        union { bf16x8 v; bf16s h[8]; } a, b, o;
        a.v = *(const bf16x8*)((const bf16s*)sd.p0 + r0o);
        b.v = *(const bf16x8*)((const bf16s*)sd.p1 + r1o);
#pragma unroll
        for (int j = 0; j < 8; ++j)
          o.h[j] = __float2bfloat16(__bfloat162float(a.h[j]) + __bfloat162float(b.h[j]));
        *(bf16x8*)(gA + (size_t)(i * 256 + tid) * 8) = o.v;
      }
    }
#pragma unroll
    for (int i = 0; i < 2; ++i)
      async_copy16(gB + (size_t)(i * 256 + tid) * 8,
                   W + (size_t)(i * 32 + ra) * 384 + ks * 64 + cs);
    __syncthreads();
#pragma unroll
    for (int kss = 0; kss < 2; ++kss) {
      const int rk = kss ? rk1 : rk0;
      bf16x8 av[4], bv[2];
#pragma unroll
      for (int f = 0; f < 4; ++f)
        av[f] = *(const bf16x8*)(gA + (size_t)(wmG + f * 16 + (lane & 15)) * 64 + rk);
#pragma unroll
      for (int f = 0; f < 2; ++f)
        bv[f] = *(const bf16x8*)(gB + (size_t)(wnG + f * 16 + (lane & 15)) * 64 + rk);
#pragma unroll
      for (int i = 0; i < 4; ++i)
#pragma unroll
        for (int j = 0; j < 2; ++j)
          gacc[i][j] = __builtin_amdgcn_mfma_f32_16x16x32_bf16(av[i], bv[j], gacc[i][j], 0, 0, 0);
    }
    __syncthreads();
  }

  // ---- GRU update epilogue ----
  const float* r32 = layer ? P.r32_1 : P.r32_0;
  float* h32 = layer ? P.h32_1 : P.h32_0;
  bf16s* hT  = layer ? P.hT1  : P.hT0;
  bf16s* hbf = layer ? P.hbf1 : P.hbf0;
  const int rq = (lane >> 4) * 4, cl = lane & 15;
#pragma unroll
  for (int fm = 0; fm < 4; ++fm)
#pragma unroll
    for (int fn = 0; fn < 2; ++fn) {
      const int d = wnG + fn * 16 + cl;
      const float bias_d = bias[d];
#pragma unroll
      for (int q = 0; q < 4; ++q) {
        int vrow = wmG + fm * 16 + rq + q;
        size_t gm = (size_t)(b0 + (vrow >> 6)) * 2048 + m0 + (vrow & 63);
        float hc = tanhf(gacc[fm][fn][q] + bias_d);
        float r = r32[gm * 64 + d];
        float h = h32[gm * 64 + d];
        float hn = r * h + (1.f - r) * hc;
        h32[gm * 64 + d] = hn;
        int b = (int)(gm >> 11), n = (int)(gm & 2047);
        hT[((size_t)(b * 64 + d)) * 2048 + n] = __float2bfloat16(hn);
        hbf[gm * 64 + d] = __float2bfloat16(hn);
        size_t xi = (((size_t)b * kT + t) * 2048 + n) * 64 + d;
        if (!layer) {
          P.x1cur[gm * 64 + d] = __float2bfloat16(P.x[xi] + hn);
          if (t == kT - 1) P.outHid[gm * 64 + d] = hn;
        } else {
          P.outCur[xi] = P.x[xi] + hn;
          if (t == kT - 1) (P.outHid + kBND)[gm * 64 + d] = hn;
        }
      }
    }
}

// ---------------- utility kernels ----------------
__global__ __launch_bounds__(256) void transpose_cvt(
    const float* in, bf16s* out, int nrows, int ncols,
    size_t in_ostride, size_t out_ostride)
{
  __shared__ float tile[64][65];
  const int r0 = blockIdx.x * 64, c0 = blockIdx.y * 64;
  in  += (size_t)blockIdx.z * in_ostride;
  out += (size_t)blockIdx.z * out_ostride;
  const int tx = threadIdx.x & 63, ty = threadIdx.x >> 6;
#pragma unroll
  for (int i = 0; i < 64; i += 4)
    tile[ty + i][tx] = in[(size_t)(r0 + ty + i) * ncols + c0 + tx];
  __syncthreads();
#pragma unroll
  for (int i = 0; i < 64; i += 4)
    out[(size_t)(c0 + ty + i) * nrows + r0 + tx] = __float2bfloat16(tile[tx][ty + i]);
}

__global__ __launch_bounds__(256) void k_cvt(const float* in, bf16s* out, int n)
{
  int i = blockIdx.x * 256 + threadIdx.x;
  if (i < n) out[i] = __float2bfloat16(in[i]);
}

__global__ __launch_bounds__(256) void k_repack(
    const float* Wg, const float* Wu, bf16s* WgT, bf16s* WuT)
{
  int idx = blockIdx.x * 256 + threadIdx.x;
  if (idx < 2 * 3 * 128 * 128) {
    int o = idx & 127, cin = (idx >> 7) & 127, k = (idx >> 14) % 3, l = idx / 49152;
    WgT[((size_t)(l * 128 + o)) * 384 + (2 * k + (cin >> 6)) * 64 + (cin & 63)] =
        __float2bfloat16(Wg[idx]);
  }
  if (idx < 2 * 3 * 128 * 64) {
    int o = idx & 63, cin = (idx >> 6) & 127, k = (idx >> 13) % 3, l = idx / 24576;
    WuT[((size_t)(l * 64 + o)) * 384 + (2 * k + (cin >> 6)) * 64 + (cin & 63)] =
        __float2bfloat16(Wu[idx]);
  }
}

__global__ __launch_bounds__(256) void init_layer(
    const float* ist_l, float* h32, bf16s* hT, bf16s* h_bf)
{
  size_t idx = (size_t)blockIdx.x * 256 + threadIdx.x;
  if (idx >= kBND) return;
  int d = (int)(idx & 63);
  size_t row = idx >> 6;
  int n = (int)(row & 2047), b = (int)(row >> 11);
  float h = ist_l[idx];
  h32[idx] = h;
  hT[((size_t)(b * 64 + d)) * 2048 + n] = __float2bfloat16(h);
  h_bf[idx] = __float2bfloat16(h);
}

// ---------------- host orchestration ----------------
extern "C" void kernel_launch(void* const* d_in, const int* in_sizes, int n_in,
                              void* d_out, int out_size, void* d_ws, size_t ws_size,
                              hipStream_t stream)
{
  (void)in_sizes; (void)n_in; (void)out_size; (void)ws_size;
  const float* x   = (const float*)d_in[0];
  const float* ist = (const float*)d_in[1];
  const float* adj = (const float*)d_in[2];
  const float* Wg  = (const float*)d_in[3];
  const float* bg  = (const float*)d_in[4];
  const float* Wu  = (const float*)d_in[5];
  const float* bu  = (const float*)d_in[6];
  float* outCur = (float*)d_out;
  float* outHid = outCur + (size_t)kB * kT * kN * kD;

  char* p = (char*)d_ws;
  auto carve = [&](size_t bytes) { char* q = p; p += (bytes + 255) & ~(size_t)255; return q; };
  bf16s* A_bf  = (bf16s*)carve((size_t)2048 * 2048 * 2);
  bf16s* A2_bf = (bf16s*)carve((size_t)2048 * 2048 * 2);
  bf16s* WgT   = (bf16s*)carve((size_t)2 * 128 * 384 * 2);
  bf16s* WuT   = (bf16s*)carve((size_t)2 * 64 * 384 * 2);
  float* h32b  = (float*)carve(2 * kBND * 4);
  float* r32b  = (float*)carve(2 * kBND * 4);
  bf16s* hTb   = (bf16s*)carve(2 * kBND * 2);
  bf16s* hbfb  = (bf16s*)carve(2 * kBND * 2);
  bf16s* zhTb  = (bf16s*)carve(2 * kBND * 2);
  bf16s* zhbfb = (bf16s*)carve(2 * kBND * 2);
  bf16s* x1b   = (bf16s*)carve(2 * kBND * 2);
  bf16s* sAh0  = (bf16s*)carve(kBND * 2);
  bf16s* sA2h0 = (bf16s*)carve(kBND * 2);
  bf16s* sAh1  = (bf16s*)carve(kBND * 2);
  bf16s* sA2h1 = (bf16s*)carve(kBND * 2);
  bf16s* sZ0   = (bf16s*)carve(kBND * 2);
  bf16s* sA2Z0 = (bf16s*)carve(kBND * 2);
  bf16s* sZ1   = (bf16s*)carve(kBND * 2);
  bf16s* sA2Z1 = (bf16s*)carve(kBND * 2);
  const size_t xTfull = (size_t)kB * kT * kD * kN * 2;   // 96 MiB
  bf16s* AxF  = (bf16s*)carve(xTfull);
  bf16s* A2xF = (bf16s*)carve(xTfull);
  bf16s* xTh  = (bf16s*)carve(xTfull / 2);
  bf16s* AT_bf = AxF;   // alias: AT dead (after k_a2) before AxF is written

  float* h32_0 = h32b;   float* h32_1 = h32b + kBND;
  float* r32_0 = r32b;   float* r32_1 = r32b + kBND;
  bf16s* hT0 = hTb;      bf16s* hT1 = hTb + kBND;
  bf16s* hbf0 = hbfb;    bf16s* hbf1 = hbfb + kBND;
  bf16s* zhT0 = zhTb;    bf16s* zhT1 = zhTb + kBND;
  bf16s* zhbf0 = zhbfb;  bf16s* zhbf1 = zhbfb + kBND;

  // ---- setup ----
  k_cvt<<<dim3((2048 * 2048 + 255) / 256), 256, 0, stream>>>(adj, A_bf, 2048 * 2048);
  transpose_cvt<<<dim3(32, 32, 1), 256, 0, stream>>>(adj, AT_bf, 2048, 2048, 0, 0);
  k_a2<<<dim3(16, 16, 1), 256, 0, stream>>>(A_bf, AT_bf, A2_bf);
  k_repack<<<dim3(384), 256, 0, stream>>>(Wg, Wu, WgT, WuT);
  init_layer<<<dim3((int)(kBND / 256)), 256, 0, stream>>>(ist, h32_0, hT0, hbf0);
  init_layer<<<dim3((int)(kBND / 256)), 256, 0, stream>>>(ist + kBND, h32_1, hT1, hbf1);

  // ---- batched layer-0 x-diffusion (two b-halves) ----
  for (int h = 0; h < 2; ++h) {
    size_t off = (size_t)h * 8 * kT * 131072;
    transpose_cvt<<<dim3(32, 1, 8 * kT), 256, 0, stream>>>(x + off, xTh, 2048, 64, 131072, 131072);
    DiffP dp; dp.S0 = A_bf; dp.S1 = A2_bf; dp.colsPerGrp = 12288;
    dp.g[0] = DiffGrp{xTh, AxF + off, A2xF + off};
    dp.g[1] = dp.g[2] = dp.g[3] = DiffGrp{nullptr, nullptr, nullptr};
    k_diff<<<dim3(32, 96), 256, 0, stream>>>(dp);
  }

  auto Sb = [](const void* p0, int astr, int trow) { return Slot{p0, nullptr, astr, trow, 0, 0, 0}; };
  auto Sf = [](const void* p0, int astr, int trow) { return Slot{p0, nullptr, astr, trow, 0, 0, 1}; };
  auto S2 = [](const void* p0, const void* p1, int astr1, int trow1) {
    return Slot{p0, p1, 2048, 0, astr1, trow1, 2};
  };

  // ---- pipelined supersteps: s runs cell(0,s) and cell(1,s-1); 3 launches/step ----
  for (int s = 0; s <= kT; ++s) {
    const bool aA = (s < kT), aB = (s >= 1);
    const int tA = s, tB = s - 1;
    const int nA = aA ? 256 : 0, nB = aB ? 256 : 0;
    bf16s* x1cur  = x1b + (size_t)(s & 1) * kBND;
    bf16s* x1prev = x1b + (size_t)((s - 1) & 1) * kBND;

    // launch 1: phase-0 diffusion (h0 always; h1 if aB)
    {
      DiffP dp; dp.S0 = A_bf; dp.S1 = A2_bf; dp.colsPerGrp = 1024;
      int ng = 0;
      dp.g[ng++] = DiffGrp{hT0, sAh0, sA2h0};
      if (aB) dp.g[ng++] = DiffGrp{hT1, sAh1, sA2h1};
      for (int i = ng; i < 4; ++i) dp.g[i] = DiffGrp{nullptr, nullptr, nullptr};
      k_diff<<<dim3(32, 8 * ng), 256, 0, stream>>>(dp);
    }

    // launch 2: gate
    {
      LayerG GA = {}, GB = {};
      if (aA) {
        GA.sl.s[0] = Sf(x, kT * 2048, tA * 2048);
        GA.sl.s[1] = Sb(hbf0, 2048, 0);
        GA.sl.s[2] = Sb(AxF, kT * 2048, tA * 2048);
        GA.sl.s[3] = Sb(sAh0, 2048, 0);
        GA.sl.s[4] = Sb(A2xF, kT * 2048, tA * 2048);
        GA.sl.s[5] = Sb(sA2h0, 2048, 0);
        GA.W = WgT; GA.bias = bg; GA.h = h32_0; GA.zh = zhbf0; GA.zhT = zhT0; GA.r = r32_0;
      }
      if (aB) {
        GB.sl.s[0] = Sb(x1prev, 2048, 0);
        GB.sl.s[1] = Sb(hbf1, 2048, 0);
        GB.sl.s[2] = S2(sAh0, AxF, kT * 2048, tB * 2048);   // A@x1 = A@h0 + A@x
        GB.sl.s[3] = Sb(sAh1, 2048, 0);
        GB.sl.s[4] = S2(sA2h0, A2xF, kT * 2048, tB * 2048);
        GB.sl.s[5] = Sb(sA2h1, 2048, 0);
        GB.W = WgT + (size_t)128 * 384; GB.bias = bg + 128;
        GB.h = h32_1; GB.zh = zhbf1; GB.zhT = zhT1; GB.r = r32_1;
      }
      k_gate<<<dim3(nA + nB), 256, 0, stream>>>(GA, GB, nA);
    }

    // launch 3: fused zh-diffusion + candidate + GRU update
    {
      CandP P;
      P.A = A_bf; P.A2 = A2_bf;
      P.zhT0 = zhT0; P.zhT1 = zhT1;
      P.sZ0 = sZ0; P.sA2Z0 = sA2Z0; P.sZ1 = sZ1; P.sA2Z1 = sA2Z1;
      P.x = x; P.zhbf0 = zhbf0; P.zhbf1 = zhbf1; P.x1prev = x1prev;
      P.AxF = AxF; P.A2xF = A2xF; P.sAh0 = sAh0; P.sA2h0 = sA2h0;
      P.WuT = WuT; P.bu = bu;
      P.r32_0 = r32_0; P.r32_1 = r32_1;
      P.h32_0 = h32_0; P.h32_1 = h32_1;
      P.hT0 = hT0; P.hT1 = hT1; P.hbf0 = hbf0; P.hbf1 = hbf1;
      P.x1cur = x1cur; P.outCur = outCur; P.outHid = outHid;
      P.tA = tA; P.tB = tB; P.aA = aA ? 1 : 0; P.aB = aB ? 1 : 0;
      k_dcand<<<dim3(512), 256, 0, stream>>>(P);
    }
  }
}